// Round 1
// baseline (31074.243 us; speedup 1.0000x reference)
//
#include <hip/hip_runtime.h>

#define BB 8
#define CC 64
#define NPTS 32768
#define RR 32
#define RV 32768            // 32^3
#define MTOT (BB*RV)        // 262144
#define EPSV 1e-4f

// ws float offsets
#define OFF_BUFA 0u               // 16777216  grid sums / x2
#define OFF_BUFB 16777216u        // 16777216  v ndhwc
#define OFF_NORM 33554432u        // 786432
#define OFF_CNT  34340864u        // 262144
#define OFF_MEAN 34603008u        // 24
#define OFF_S1   34603032u        // 128
#define OFF_S2   34603160u        // 128
#define OFF_SP   34603288u        // 128
#define OFF_WT1  34603416u        // 110592
#define OFF_WT2  34714008u        // 110592
#define WS_FLOATS 34824600u

__global__ void k_coord_mean(const float* __restrict__ coords, float* __restrict__ mean) {
    int ba = blockIdx.x;                 // b*3 + axis, 24 blocks
    const float* src = coords + (size_t)ba * NPTS;
    float s = 0.f;
    for (int i = threadIdx.x; i < NPTS; i += 256) s += src[i];
    __shared__ float red[256];
    red[threadIdx.x] = s; __syncthreads();
    for (int w = 128; w > 0; w >>= 1) {
        if (threadIdx.x < w) red[threadIdx.x] += red[threadIdx.x + w];
        __syncthreads();
    }
    if (threadIdx.x == 0) mean[ba] = red[0] * (1.0f / NPTS);
}

__global__ void k_voxelize(const float* __restrict__ coords, const float* __restrict__ feats,
                           const float* __restrict__ mean, float* __restrict__ sums,
                           float* __restrict__ cnt, float* __restrict__ norm) {
    int idx = blockIdx.x * 256 + threadIdx.x;      // b*NPTS + n
    int b = idx >> 15, n = idx & (NPTS - 1);
    int flat = 0;
    #pragma unroll
    for (int a = 0; a < 3; ++a) {
        float c = coords[((size_t)(b * 3 + a)) * NPTS + n];
        float nm = (c - mean[b * 3 + a] + 1.0f) * (0.5f * RR);
        nm = fminf(fmaxf(nm, 0.0f), (float)(RR - 1));
        norm[((size_t)(b * 3 + a)) * NPTS + n] = nm;
        flat = flat * RR + (int)rintf(nm);
    }
    atomicAdd(&cnt[b * RV + flat], 1.0f);
    float* dst = &sums[(size_t)(b * RV + flat) * CC];
    for (int c0 = 0; c0 < CC; ++c0)
        atomicAdd(&dst[c0], feats[((size_t)(b * CC + c0)) * NPTS + n]);
}

__global__ void k_avg(float* __restrict__ sums, const float* __restrict__ cnt) {
    size_t i = (size_t)blockIdx.x * 256 + threadIdx.x;   // MTOT*CC elems
    float cn = cnt[i >> 6];
    sums[i] = sums[i] / fmaxf(cn, 1.0f);
}

__global__ void k_wt(const float* __restrict__ w, float* __restrict__ wT) {
    int i = blockIdx.x * 256 + threadIdx.x;              // CC*CC*27
    if (i >= CC * CC * 27) return;
    int tap = i % 27, t = i / 27;
    int ci = t & 63, co = t >> 6;
    wT[((size_t)(co * 27 + tap)) * CC + ci] = w[i];
}

__global__ __launch_bounds__(256) void k_conv(const float* __restrict__ x, const float* __restrict__ wT,
                                              const float* __restrict__ bias, float* __restrict__ y) {
    int gvox = blockIdx.x * 4 + (threadIdx.x >> 6);
    int co = threadIdx.x & 63;
    int b = gvox >> 15, r3 = gvox & 32767;
    int d = r3 >> 10, h = (r3 >> 5) & 31, wv = r3 & 31;
    float acc = 0.f;
    for (int kd = 0; kd < 3; ++kd) {
        int dd = d + kd - 1; if ((unsigned)dd >= 32u) continue;
        for (int kh = 0; kh < 3; ++kh) {
            int hh = h + kh - 1; if ((unsigned)hh >= 32u) continue;
            for (int kw = 0; kw < 3; ++kw) {
                int ww = wv + kw - 1; if ((unsigned)ww >= 32u) continue;
                size_t nvox = (size_t)((b << 15) | (dd << 10) | (hh << 5) | ww);
                const float4* xin = (const float4*)&x[nvox * CC];
                int tap = (kd * 3 + kh) * 3 + kw;
                const float4* wp = (const float4*)&wT[((size_t)(co * 27 + tap)) * CC];
                #pragma unroll
                for (int q = 0; q < 16; ++q) {
                    float4 a = xin[q], wq = wp[q];
                    acc += a.x * wq.x + a.y * wq.y + a.z * wq.z + a.w * wq.w;
                }
            }
        }
    }
    y[(size_t)gvox * CC + co] = acc + bias[co];
}

// stats for channel-innermost layout (idx & 63 == channel)
__global__ void k_stats_ci(const float* __restrict__ x, float* __restrict__ stats) {
    int c = threadIdx.x & 63;
    float s = 0.f, s2 = 0.f;
    for (size_t i = (size_t)blockIdx.x * 256 + threadIdx.x; i < (size_t)MTOT * CC; i += (size_t)256 * 256) {
        float v = x[i]; s += v; s2 += v * v;
    }
    __shared__ float red[512];
    red[threadIdx.x] = s; red[256 + threadIdx.x] = s2;
    __syncthreads();
    if (threadIdx.x < 64) {
        s  = red[threadIdx.x] + red[threadIdx.x + 64] + red[threadIdx.x + 128] + red[threadIdx.x + 192];
        s2 = red[256 + threadIdx.x] + red[256 + threadIdx.x + 64] + red[256 + threadIdx.x + 128] + red[256 + threadIdx.x + 192];
        atomicAdd(&stats[c], s);
        atomicAdd(&stats[64 + c], s2);
    }
}

__global__ void k_bn_ci(const float* __restrict__ y, const float* __restrict__ stats,
                        const float* __restrict__ g, const float* __restrict__ bb,
                        float* __restrict__ out) {
    size_t i = (size_t)blockIdx.x * 256 + threadIdx.x;
    int c = (int)(i & 63);
    float mu = stats[c] * (1.0f / MTOT);
    float var = stats[64 + c] * (1.0f / MTOT) - mu * mu;
    float v = (y[i] - mu) * rsqrtf(var + EPSV) * g[c] + bb[c];
    out[i] = v > 0.f ? v : 0.1f * v;
}

// NDHWC -> NCDHW (64-vox x 64-ch tiles)
__global__ void k_transpose(const float* __restrict__ in, float* __restrict__ out) {
    __shared__ float t[64 * 65];
    size_t base = (size_t)blockIdx.x * 4096;
    int gv0 = blockIdx.x * 64;
    int b = gv0 >> 15;
    int vox0 = gv0 & 32767;
    #pragma unroll
    for (int k = 0; k < 16; ++k) {
        int idx = k * 256 + threadIdx.x;
        t[(idx >> 6) * 65 + (idx & 63)] = in[base + idx];
    }
    __syncthreads();
    #pragma unroll
    for (int k = 0; k < 16; ++k) {
        int idx = k * 256 + threadIdx.x;
        int ch = idx >> 6, voxl = idx & 63;
        out[((size_t)(b * 64 + ch)) * RV + vox0 + voxl] = t[voxl * 65 + ch];
    }
}

__global__ void k_mlp(const float* __restrict__ f, const float* __restrict__ w,
                      const float* __restrict__ bias, float* __restrict__ p) {
    __shared__ float wl[64 * 64];            // wl[ci*64+co]
    for (int k = threadIdx.x; k < 4096; k += 256) wl[k] = w[(k & 63) * 64 + (k >> 6)];
    __syncthreads();
    int b = blockIdx.x >> 7;
    int n0 = (blockIdx.x & 127) * 256 + threadIdx.x;
    float acc[64];
    #pragma unroll
    for (int co = 0; co < 64; ++co) acc[co] = 0.f;
    for (int ci = 0; ci < 64; ++ci) {
        float fv = f[((size_t)(b * 64 + ci)) * NPTS + n0];
        #pragma unroll
        for (int co = 0; co < 64; ++co) acc[co] += fv * wl[ci * 64 + co];
    }
    for (int co = 0; co < 64; ++co)
        p[((size_t)(b * 64 + co)) * NPTS + n0] = acc[co] + bias[co];
}

// stats for (B, C, N) layout: block per (b, c)
__global__ void k_stats_bcn(const float* __restrict__ x, float* __restrict__ stats) {
    int bc = blockIdx.x;                    // 512 blocks
    int c = bc & 63;
    const float* src = x + (size_t)bc * NPTS;
    float s = 0.f, s2 = 0.f;
    for (int i = threadIdx.x; i < NPTS; i += 256) { float v = src[i]; s += v; s2 += v * v; }
    __shared__ float red[512];
    red[threadIdx.x] = s; red[256 + threadIdx.x] = s2;
    __syncthreads();
    for (int w = 128; w > 0; w >>= 1) {
        if (threadIdx.x < w) {
            red[threadIdx.x] += red[threadIdx.x + w];
            red[256 + threadIdx.x] += red[256 + threadIdx.x + w];
        }
        __syncthreads();
    }
    if (threadIdx.x == 0) { atomicAdd(&stats[c], red[0]); atomicAdd(&stats[64 + c], red[256]); }
}

__global__ void k_final(float* __restrict__ p, const float* __restrict__ stats,
                        const float* __restrict__ g, const float* __restrict__ bb,
                        const float* __restrict__ vgrid, const float* __restrict__ norm) {
    int t = blockIdx.x;                      // 65536 blocks
    int ntile = t & 127; int bc = t >> 7;    // bc = b*64 + co
    int b = bc >> 6, co = bc & 63;
    int n = ntile * 256 + threadIdx.x;
    size_t pi = (size_t)bc * NPTS + n;

    float mu = stats[co] * (1.0f / MTOT);
    float var = stats[64 + co] * (1.0f / MTOT) - mu * mu;
    float pv = (p[pi] - mu) * rsqrtf(var + EPSV) * g[co] + bb[co];
    pv = pv > 0.f ? pv : 0.1f * pv;

    float n0 = norm[((size_t)(b * 3 + 0)) * NPTS + n];
    float n1 = norm[((size_t)(b * 3 + 1)) * NPTS + n];
    float n2 = norm[((size_t)(b * 3 + 2)) * NPTS + n];
    int lx = (int)floorf(n0), ly = (int)floorf(n1), lz = (int)floorf(n2);
    float fx = n0 - (float)lx, fy = n1 - (float)ly, fz = n2 - (float)lz;
    int hx = min(lx + 1, 31), hy = min(ly + 1, 31), hz = min(lz + 1, 31);
    const float* gb = vgrid + ((size_t)b << 15) * CC;

    float s = 0.f;
    #pragma unroll
    for (int dx = 0; dx < 2; ++dx) {
        int ix = dx ? hx : lx; float wx = dx ? fx : 1.f - fx;
        #pragma unroll
        for (int dy = 0; dy < 2; ++dy) {
            int iy = dy ? hy : ly; float wy = dy ? fy : 1.f - fy;
            #pragma unroll
            for (int dz = 0; dz < 2; ++dz) {
                int iz = dz ? hz : lz; float wz = dz ? fz : 1.f - fz;
                int idx = (ix * 32 + iy) * 32 + iz;
                s += gb[(size_t)idx * CC + co] * (wx * wy * wz);
            }
        }
    }
    p[pi] = s + pv;
}

extern "C" void kernel_launch(void* const* d_in, const int* in_sizes, int n_in,
                              void* d_out, int out_size, void* d_ws, size_t ws_size,
                              hipStream_t stream) {
    const float* features = (const float*)d_in[0];
    const float* coords   = (const float*)d_in[1];
    const float* conv1_w  = (const float*)d_in[2];
    const float* conv1_b  = (const float*)d_in[3];
    const float* bn1_g    = (const float*)d_in[4];
    const float* bn1_b    = (const float*)d_in[5];
    const float* conv2_w  = (const float*)d_in[6];
    const float* conv2_b  = (const float*)d_in[7];
    const float* bn2_g    = (const float*)d_in[8];
    const float* bn2_b    = (const float*)d_in[9];
    const float* mlp_w    = (const float*)d_in[10];
    const float* mlp_b    = (const float*)d_in[11];
    const float* bnp_g    = (const float*)d_in[12];
    const float* bnp_b    = (const float*)d_in[13];

    float* ws    = (float*)d_ws;
    float* bufA  = ws + OFF_BUFA;
    float* bufB  = ws + OFF_BUFB;
    float* nrm   = ws + OFF_NORM;
    float* cnt   = ws + OFF_CNT;
    float* mean  = ws + OFF_MEAN;
    float* s1    = ws + OFF_S1;
    float* s2    = ws + OFF_S2;
    float* sp    = ws + OFF_SP;
    float* wT1   = ws + OFF_WT1;
    float* wT2   = ws + OFF_WT2;

    float* outF  = (float*)d_out;                       // fused region, also p scratch
    float* outV  = (float*)d_out + (size_t)16777216;    // v region, also conv y scratch

    // zero accumulators
    hipMemsetAsync(bufA, 0, (size_t)16777216 * 4, stream);
    hipMemsetAsync(cnt, 0, (size_t)(262144 + 24 + 384) * 4, stream);

    k_coord_mean<<<24, 256, 0, stream>>>(coords, mean);
    k_voxelize<<<1024, 256, 0, stream>>>(coords, features, mean, bufA, cnt, nrm);
    k_avg<<<65536, 256, 0, stream>>>(bufA, cnt);

    k_wt<<<432, 256, 0, stream>>>(conv1_w, wT1);
    k_wt<<<432, 256, 0, stream>>>(conv2_w, wT2);

    // conv1: bufA -> outV(raw y1)
    k_conv<<<65536, 256, 0, stream>>>(bufA, wT1, conv1_b, outV);
    k_stats_ci<<<256, 256, 0, stream>>>(outV, s1);
    k_bn_ci<<<65536, 256, 0, stream>>>(outV, s1, bn1_g, bn1_b, bufA);   // x2 -> bufA

    // conv2: bufA -> outV(raw y2)
    k_conv<<<65536, 256, 0, stream>>>(bufA, wT2, conv2_b, outV);
    k_stats_ci<<<256, 256, 0, stream>>>(outV, s2);
    k_bn_ci<<<65536, 256, 0, stream>>>(outV, s2, bn2_g, bn2_b, bufB);   // v ndhwc -> bufB

    // v -> d_out (NCDHW)
    k_transpose<<<4096, 256, 0, stream>>>(bufB, outV);

    // point branch: p -> outF
    k_mlp<<<1024, 256, 0, stream>>>(features, mlp_w, mlp_b, outF);
    k_stats_bcn<<<512, 256, 0, stream>>>(outF, sp);

    // fuse (in-place over p)
    k_final<<<65536, 256, 0, stream>>>(outF, sp, bnp_g, bnp_b, bufB, nrm);
}

// Round 2
// 2785.774 us; speedup vs baseline: 11.1546x; 11.1546x over previous
//
#include <hip/hip_runtime.h>
#include <hip/hip_bf16.h>

#define BB 8
#define CC 64
#define NPTS 32768
#define RR 32
#define RV 32768            // 32^3
#define MTOT (BB*RV)        // 262144
#define EPSV 1e-4f

// ws float offsets
#define OFF_BUFA 0u               // 16777216 f32: grid sums, later conv2 raw out
#define OFF_BUFB 16777216u        // 16777216 f32: [0:8388608] = xb (bf16 x 16.7M), later full = v ndhwc f32
#define OFF_WB1  25165824u        // 55296 float-slots = 110592 bf16 (dead once v written)
#define OFF_WB2  25221120u        // 55296
#define OFF_ZG   25276416u        // 64 floats zero guard
#define OFF_NORM 33554432u        // 786432
#define OFF_CNT  34340864u        // 262144
#define OFF_MEAN 34603008u        // 24
#define OFF_S1   34603032u        // 128
#define OFF_S2   34603160u        // 128
#define OFF_SP   34603288u        // 128

typedef __attribute__((ext_vector_type(8))) __bf16 bf16x8;
typedef __attribute__((ext_vector_type(4))) float f32x4;

__global__ void k_coord_mean(const float* __restrict__ coords, float* __restrict__ mean) {
    int ba = blockIdx.x;                 // b*3 + axis, 24 blocks
    const float* src = coords + (size_t)ba * NPTS;
    float s = 0.f;
    for (int i = threadIdx.x; i < NPTS; i += 256) s += src[i];
    __shared__ float red[256];
    red[threadIdx.x] = s; __syncthreads();
    for (int w = 128; w > 0; w >>= 1) {
        if (threadIdx.x < w) red[threadIdx.x] += red[threadIdx.x + w];
        __syncthreads();
    }
    if (threadIdx.x == 0) mean[ba] = red[0] * (1.0f / NPTS);
}

__global__ void k_voxelize(const float* __restrict__ coords, const float* __restrict__ feats,
                           const float* __restrict__ mean, float* __restrict__ sums,
                           float* __restrict__ cnt, float* __restrict__ norm) {
    int idx = blockIdx.x * 256 + threadIdx.x;      // b*NPTS + n
    int b = idx >> 15, n = idx & (NPTS - 1);
    int flat = 0;
    #pragma unroll
    for (int a = 0; a < 3; ++a) {
        float c = coords[((size_t)(b * 3 + a)) * NPTS + n];
        float nm = (c - mean[b * 3 + a] + 1.0f) * (0.5f * RR);
        nm = fminf(fmaxf(nm, 0.0f), (float)(RR - 1));
        norm[((size_t)(b * 3 + a)) * NPTS + n] = nm;
        flat = flat * RR + (int)rintf(nm);
    }
    atomicAdd(&cnt[b * RV + flat], 1.0f);
    float* dst = &sums[(size_t)(b * RV + flat) * CC];
    for (int c0 = 0; c0 < CC; ++c0)
        atomicAdd(&dst[c0], feats[((size_t)(b * CC + c0)) * NPTS + n]);
}

__global__ void k_avg_bf16(const float* __restrict__ sums, const float* __restrict__ cnt,
                           __hip_bfloat16* __restrict__ xb) {
    size_t i = (size_t)blockIdx.x * 256 + threadIdx.x;   // MTOT*CC elems
    float cn = cnt[i >> 6];
    xb[i] = __float2bfloat16(sums[i] / fmaxf(cn, 1.0f));
}

// conv_w (co,ci,kd,kh,kw) -> wb[tap][co][ci] bf16
__global__ void k_wb(const float* __restrict__ w, __hip_bfloat16* __restrict__ wb) {
    int i = blockIdx.x * 256 + threadIdx.x;              // CC*CC*27
    if (i >= CC * CC * 27) return;
    int tap = i % 27, t = i / 27;
    int ci = t & 63, co = t >> 6;
    wb[((size_t)(tap * 64 + co)) * 64 + ci] = __float2bfloat16(w[i]);
}

// implicit-GEMM conv: y[m, co] = sum_{tap,ci} xb[shift(m,tap), ci] * wb[tap][co][ci] + bias
// block: 4 waves, 64 voxels x 64 co; wave: 16 voxels x 64 co (4 C-frags)
__global__ __launch_bounds__(256) void k_conv_mfma(
    const ushort* __restrict__ xb, const ushort* __restrict__ wb,
    const float* __restrict__ bias, float* __restrict__ y,
    const ushort* __restrict__ zg) {
    int wid = threadIdx.x >> 6, lane = threadIdx.x & 63;
    int kg = lane >> 4, nl = lane & 15;
    int m = blockIdx.x * 64 + wid * 16 + nl;             // A-row voxel for this lane
    int b = m >> 15, d = (m >> 10) & 31, h = (m >> 5) & 31, w = m & 31;
    f32x4 acc[4];
    #pragma unroll
    for (int cb = 0; cb < 4; ++cb) acc[cb] = (f32x4){0.f, 0.f, 0.f, 0.f};

    #pragma unroll 1
    for (int tap = 0; tap < 27; ++tap) {
        int kd = tap / 9, kh = (tap / 3) % 3, kw = tap % 3;
        int dd = d + kd - 1, hh = h + kh - 1, ww = w + kw - 1;
        bool valid = ((unsigned)dd < 32u) && ((unsigned)hh < 32u) && ((unsigned)ww < 32u);
        const ushort* ab = valid
            ? xb + (((size_t)((b << 15) | (dd << 10) | (hh << 5) | ww)) << 6) + kg * 8
            : zg + kg * 8;
        const ushort* bb = wb + tap * 4096 + nl * 64 + kg * 8;
        #pragma unroll
        for (int s = 0; s < 2; ++s) {
            bf16x8 af = *reinterpret_cast<const bf16x8*>(ab + s * 32);
            #pragma unroll
            for (int cb = 0; cb < 4; ++cb) {
                bf16x8 bf = *reinterpret_cast<const bf16x8*>(bb + cb * 1024 + s * 32);
                acc[cb] = __builtin_amdgcn_mfma_f32_16x16x32_bf16(af, bf, acc[cb], 0, 0, 0);
            }
        }
    }

    int vbase = blockIdx.x * 64 + wid * 16 + kg * 4;
    #pragma unroll
    for (int cb = 0; cb < 4; ++cb) {
        int co = cb * 16 + nl;
        float bs = bias[co];
        #pragma unroll
        for (int r = 0; r < 4; ++r)
            y[(((size_t)(vbase + r)) << 6) + co] = acc[cb][r] + bs;
    }
}

// stats for channel-innermost layout (idx & 63 == channel)
__global__ void k_stats_ci(const float* __restrict__ x, float* __restrict__ stats) {
    int c = threadIdx.x & 63;
    float s = 0.f, s2 = 0.f;
    for (size_t i = (size_t)blockIdx.x * 256 + threadIdx.x; i < (size_t)MTOT * CC; i += (size_t)256 * 256) {
        float v = x[i]; s += v; s2 += v * v;
    }
    __shared__ float red[512];
    red[threadIdx.x] = s; red[256 + threadIdx.x] = s2;
    __syncthreads();
    if (threadIdx.x < 64) {
        s  = red[threadIdx.x] + red[threadIdx.x + 64] + red[threadIdx.x + 128] + red[threadIdx.x + 192];
        s2 = red[256 + threadIdx.x] + red[256 + threadIdx.x + 64] + red[256 + threadIdx.x + 128] + red[256 + threadIdx.x + 192];
        atomicAdd(&stats[c], s);
        atomicAdd(&stats[64 + c], s2);
    }
}

__global__ void k_bn_ci_bf16(const float* __restrict__ y, const float* __restrict__ stats,
                             const float* __restrict__ g, const float* __restrict__ bb,
                             __hip_bfloat16* __restrict__ out) {
    size_t i = (size_t)blockIdx.x * 256 + threadIdx.x;
    int c = (int)(i & 63);
    float mu = stats[c] * (1.0f / MTOT);
    float var = stats[64 + c] * (1.0f / MTOT) - mu * mu;
    float v = (y[i] - mu) * rsqrtf(var + EPSV) * g[c] + bb[c];
    out[i] = __float2bfloat16(v > 0.f ? v : 0.1f * v);
}

__global__ void k_bn_ci_f32(const float* __restrict__ y, const float* __restrict__ stats,
                            const float* __restrict__ g, const float* __restrict__ bb,
                            float* __restrict__ out) {
    size_t i = (size_t)blockIdx.x * 256 + threadIdx.x;
    int c = (int)(i & 63);
    float mu = stats[c] * (1.0f / MTOT);
    float var = stats[64 + c] * (1.0f / MTOT) - mu * mu;
    float v = (y[i] - mu) * rsqrtf(var + EPSV) * g[c] + bb[c];
    out[i] = v > 0.f ? v : 0.1f * v;
}

// NDHWC -> NCDHW (64-vox x 64-ch tiles)
__global__ void k_transpose(const float* __restrict__ in, float* __restrict__ out) {
    __shared__ float t[64 * 65];
    size_t base = (size_t)blockIdx.x * 4096;
    int gv0 = blockIdx.x * 64;
    int b = gv0 >> 15;
    int vox0 = gv0 & 32767;
    #pragma unroll
    for (int k = 0; k < 16; ++k) {
        int idx = k * 256 + threadIdx.x;
        t[(idx >> 6) * 65 + (idx & 63)] = in[base + idx];
    }
    __syncthreads();
    #pragma unroll
    for (int k = 0; k < 16; ++k) {
        int idx = k * 256 + threadIdx.x;
        int ch = idx >> 6, voxl = idx & 63;
        out[((size_t)(b * 64 + ch)) * RV + vox0 + voxl] = t[voxl * 65 + ch];
    }
}

__global__ void k_mlp(const float* __restrict__ f, const float* __restrict__ w,
                      const float* __restrict__ bias, float* __restrict__ p) {
    __shared__ float wl[64 * 64];            // wl[ci*64+co]
    for (int k = threadIdx.x; k < 4096; k += 256) wl[k] = w[(k & 63) * 64 + (k >> 6)];
    __syncthreads();
    int b = blockIdx.x >> 7;
    int n0 = (blockIdx.x & 127) * 256 + threadIdx.x;
    float acc[64];
    #pragma unroll
    for (int co = 0; co < 64; ++co) acc[co] = 0.f;
    for (int ci = 0; ci < 64; ++ci) {
        float fv = f[((size_t)(b * 64 + ci)) * NPTS + n0];
        #pragma unroll
        for (int co = 0; co < 64; ++co) acc[co] += fv * wl[ci * 64 + co];
    }
    for (int co = 0; co < 64; ++co)
        p[((size_t)(b * 64 + co)) * NPTS + n0] = acc[co] + bias[co];
}

// stats for (B, C, N) layout: block per (b, c)
__global__ void k_stats_bcn(const float* __restrict__ x, float* __restrict__ stats) {
    int bc = blockIdx.x;                    // 512 blocks
    int c = bc & 63;
    const float* src = x + (size_t)bc * NPTS;
    float s = 0.f, s2 = 0.f;
    for (int i = threadIdx.x; i < NPTS; i += 256) { float v = src[i]; s += v; s2 += v * v; }
    __shared__ float red[512];
    red[threadIdx.x] = s; red[256 + threadIdx.x] = s2;
    __syncthreads();
    for (int w = 128; w > 0; w >>= 1) {
        if (threadIdx.x < w) {
            red[threadIdx.x] += red[threadIdx.x + w];
            red[256 + threadIdx.x] += red[256 + threadIdx.x + w];
        }
        __syncthreads();
    }
    if (threadIdx.x == 0) { atomicAdd(&stats[c], red[0]); atomicAdd(&stats[64 + c], red[256]); }
}

__global__ void k_final(float* __restrict__ p, const float* __restrict__ stats,
                        const float* __restrict__ g, const float* __restrict__ bb,
                        const float* __restrict__ vgrid, const float* __restrict__ norm) {
    int t = blockIdx.x;                      // 65536 blocks
    int ntile = t & 127; int bc = t >> 7;    // bc = b*64 + co
    int b = bc >> 6, co = bc & 63;
    int n = ntile * 256 + threadIdx.x;
    size_t pi = (size_t)bc * NPTS + n;

    float mu = stats[co] * (1.0f / MTOT);
    float var = stats[64 + co] * (1.0f / MTOT) - mu * mu;
    float pv = (p[pi] - mu) * rsqrtf(var + EPSV) * g[co] + bb[co];
    pv = pv > 0.f ? pv : 0.1f * pv;

    float n0 = norm[((size_t)(b * 3 + 0)) * NPTS + n];
    float n1 = norm[((size_t)(b * 3 + 1)) * NPTS + n];
    float n2 = norm[((size_t)(b * 3 + 2)) * NPTS + n];
    int lx = (int)floorf(n0), ly = (int)floorf(n1), lz = (int)floorf(n2);
    float fx = n0 - (float)lx, fy = n1 - (float)ly, fz = n2 - (float)lz;
    int hx = min(lx + 1, 31), hy = min(ly + 1, 31), hz = min(lz + 1, 31);
    const float* gb = vgrid + ((size_t)b << 15) * CC;

    float s = 0.f;
    #pragma unroll
    for (int dx = 0; dx < 2; ++dx) {
        int ix = dx ? hx : lx; float wx = dx ? fx : 1.f - fx;
        #pragma unroll
        for (int dy = 0; dy < 2; ++dy) {
            int iy = dy ? hy : ly; float wy = dy ? fy : 1.f - fy;
            #pragma unroll
            for (int dz = 0; dz < 2; ++dz) {
                int iz = dz ? hz : lz; float wz = dz ? fz : 1.f - fz;
                int idx = (ix * 32 + iy) * 32 + iz;
                s += gb[(size_t)idx * CC + co] * (wx * wy * wz);
            }
        }
    }
    p[pi] = s + pv;
}

extern "C" void kernel_launch(void* const* d_in, const int* in_sizes, int n_in,
                              void* d_out, int out_size, void* d_ws, size_t ws_size,
                              hipStream_t stream) {
    const float* features = (const float*)d_in[0];
    const float* coords   = (const float*)d_in[1];
    const float* conv1_w  = (const float*)d_in[2];
    const float* conv1_b  = (const float*)d_in[3];
    const float* bn1_g    = (const float*)d_in[4];
    const float* bn1_b    = (const float*)d_in[5];
    const float* conv2_w  = (const float*)d_in[6];
    const float* conv2_b  = (const float*)d_in[7];
    const float* bn2_g    = (const float*)d_in[8];
    const float* bn2_b    = (const float*)d_in[9];
    const float* mlp_w    = (const float*)d_in[10];
    const float* mlp_b    = (const float*)d_in[11];
    const float* bnp_g    = (const float*)d_in[12];
    const float* bnp_b    = (const float*)d_in[13];

    float* ws    = (float*)d_ws;
    float* bufA  = ws + OFF_BUFA;
    float* bufB  = ws + OFF_BUFB;
    __hip_bfloat16* xb  = (__hip_bfloat16*)(ws + OFF_BUFB);
    __hip_bfloat16* wb1 = (__hip_bfloat16*)(ws + OFF_WB1);
    __hip_bfloat16* wb2 = (__hip_bfloat16*)(ws + OFF_WB2);
    float* zg    = ws + OFF_ZG;
    float* nrm   = ws + OFF_NORM;
    float* cnt   = ws + OFF_CNT;
    float* mean  = ws + OFF_MEAN;
    float* s1    = ws + OFF_S1;
    float* s2    = ws + OFF_S2;
    float* sp    = ws + OFF_SP;

    float* outF  = (float*)d_out;                       // fused region, also p scratch
    float* outV  = (float*)d_out + (size_t)16777216;    // v region, also conv1 raw-y scratch

    // zero accumulators + guard
    hipMemsetAsync(bufA, 0, (size_t)16777216 * 4, stream);
    hipMemsetAsync(cnt, 0, (size_t)(262144 + 24 + 384) * 4, stream);
    hipMemsetAsync(zg, 0, 256, stream);

    k_coord_mean<<<24, 256, 0, stream>>>(coords, mean);
    k_voxelize<<<1024, 256, 0, stream>>>(coords, features, mean, bufA, cnt, nrm);
    k_avg_bf16<<<65536, 256, 0, stream>>>(bufA, cnt, xb);

    k_wb<<<432, 256, 0, stream>>>(conv1_w, wb1);
    k_wb<<<432, 256, 0, stream>>>(conv2_w, wb2);

    // conv1: xb -> outV (raw y1, f32 NDHWC)
    k_conv_mfma<<<4096, 256, 0, stream>>>((const ushort*)xb, (const ushort*)wb1, conv1_b, outV, (const ushort*)zg);
    k_stats_ci<<<256, 256, 0, stream>>>(outV, s1);
    k_bn_ci_bf16<<<65536, 256, 0, stream>>>(outV, s1, bn1_g, bn1_b, xb);   // x2 bf16 -> xb

    // conv2: xb -> bufA (raw y2)
    k_conv_mfma<<<4096, 256, 0, stream>>>((const ushort*)xb, (const ushort*)wb2, conv2_b, bufA, (const ushort*)zg);
    k_stats_ci<<<256, 256, 0, stream>>>(bufA, s2);
    k_bn_ci_f32<<<65536, 256, 0, stream>>>(bufA, s2, bn2_g, bn2_b, bufB);  // v ndhwc f32 -> bufB

    // v -> d_out (NCDHW)
    k_transpose<<<4096, 256, 0, stream>>>(bufB, outV);

    // point branch: p -> outF
    k_mlp<<<1024, 256, 0, stream>>>(features, mlp_w, mlp_b, outF);
    k_stats_bcn<<<512, 256, 0, stream>>>(outF, sp);

    // fuse (in-place over p)
    k_final<<<65536, 256, 0, stream>>>(outF, sp, bnp_g, bnp_b, bufB, nrm);
}

// Round 3
// 1945.936 us; speedup vs baseline: 15.9688x; 1.4316x over previous
//
#include <hip/hip_runtime.h>
#include <hip/hip_bf16.h>

#define BB 8
#define CC 64
#define NPTS 32768
#define RR 32
#define RV 32768            // 32^3
#define MTOT (BB*RV)        // 262144
#define EPSV 1e-4f

// ws float offsets
#define OFF_BUFA 0u               // 16777216 f32: featsT (B,N,C), later conv2 raw out
#define OFF_BUFB 16777216u        // 16777216 f32: [0:8388608] = xb bf16; later full = v ndhwc f32
#define OFF_WB1  25165824u        // 55296 float-slots = 110592 bf16
#define OFF_WB2  25221120u        // 55296
#define OFF_ZG   25276416u        // 64 floats zero guard
#define OFF_BASE 25276480u        // 262144 uint
#define OFF_IDX  25538624u        // 262144 uint
#define OFF_AUX  25800768u        // 256 uint
#define OFF_CELL 25801024u        // 262144 int
#define OFF_CNT  26063168u        // 262144 uint
#define OFF_MEAN 26325312u        // 24
#define OFF_NORM 33554432u        // 786432 (survives to k_final)
#define OFF_S1   34340864u        // 128
#define OFF_S2   34340992u        // 128
#define OFF_SP   34341120u        // 128

typedef __attribute__((ext_vector_type(8))) __bf16 bf16x8;
typedef __attribute__((ext_vector_type(4))) float f32x4;

__global__ void k_coord_mean(const float* __restrict__ coords, float* __restrict__ mean) {
    int ba = blockIdx.x;                 // b*3 + axis, 24 blocks
    const float* src = coords + (size_t)ba * NPTS;
    float s = 0.f;
    for (int i = threadIdx.x; i < NPTS; i += 256) s += src[i];
    __shared__ float red[256];
    red[threadIdx.x] = s; __syncthreads();
    for (int w = 128; w > 0; w >>= 1) {
        if (threadIdx.x < w) red[threadIdx.x] += red[threadIdx.x + w];
        __syncthreads();
    }
    if (threadIdx.x == 0) mean[ba] = red[0] * (1.0f / NPTS);
}

// feats (B,C,N) -> featsT (B,N,C) f32
__global__ void k_transposeF(const float* __restrict__ in, float* __restrict__ out) {
    __shared__ float t[64 * 65];
    int b = blockIdx.x >> 9;
    int n0 = (blockIdx.x & 511) * 64;
    #pragma unroll
    for (int k = 0; k < 16; ++k) {
        int idx = k * 256 + threadIdx.x;
        int c = idx >> 6, nl = idx & 63;
        t[c * 65 + nl] = in[((size_t)(b * 64 + c)) * NPTS + n0 + nl];
    }
    __syncthreads();
    #pragma unroll
    for (int k = 0; k < 16; ++k) {
        int idx = k * 256 + threadIdx.x;
        int nl = idx >> 6, c = idx & 63;
        out[((size_t)((b << 15) + n0 + nl)) * 64 + c] = t[c * 65 + nl];
    }
}

// per point: norm, cell id, count
__global__ void k_cellid(const float* __restrict__ coords, const float* __restrict__ mean,
                         float* __restrict__ norm, int* __restrict__ cellid,
                         unsigned* __restrict__ cnt) {
    int idx = blockIdx.x * 256 + threadIdx.x;      // b*NPTS + n
    int b = idx >> 15, n = idx & (NPTS - 1);
    int flat = 0;
    #pragma unroll
    for (int a = 0; a < 3; ++a) {
        float c = coords[((size_t)(b * 3 + a)) * NPTS + n];
        float nm = (c - mean[b * 3 + a] + 1.0f) * (0.5f * RR);
        nm = fminf(fmaxf(nm, 0.0f), (float)(RR - 1));
        norm[((size_t)(b * 3 + a)) * NPTS + n] = nm;
        flat = flat * RR + (int)rintf(nm);
    }
    int cell = b * RV + flat;
    cellid[idx] = cell;
    atomicAdd(&cnt[cell], 1u);
}

// block-local exclusive scan: 256 blocks x 1024 cells
__global__ void k_scan1(const unsigned* __restrict__ cnt, unsigned* __restrict__ base,
                        unsigned* __restrict__ aux) {
    int tid = threadIdx.x;
    int c0 = blockIdx.x * 1024 + tid * 4;
    unsigned v0 = cnt[c0], v1 = cnt[c0 + 1], v2 = cnt[c0 + 2], v3 = cnt[c0 + 3];
    unsigned tot = v0 + v1 + v2 + v3;
    __shared__ unsigned sc[256];
    sc[tid] = tot; __syncthreads();
    for (int off = 1; off < 256; off <<= 1) {
        unsigned t = (tid >= off) ? sc[tid - off] : 0u;
        __syncthreads();
        sc[tid] += t;
        __syncthreads();
    }
    unsigned excl = sc[tid] - tot;
    base[c0] = excl;
    base[c0 + 1] = excl + v0;
    base[c0 + 2] = excl + v0 + v1;
    base[c0 + 3] = excl + v0 + v1 + v2;
    if (tid == 255) aux[blockIdx.x] = sc[255];
}

__global__ void k_scan2(unsigned* __restrict__ aux) {
    int tid = threadIdx.x;
    unsigned own = aux[tid];
    __shared__ unsigned sc[256];
    sc[tid] = own; __syncthreads();
    for (int off = 1; off < 256; off <<= 1) {
        unsigned t = (tid >= off) ? sc[tid - off] : 0u;
        __syncthreads();
        sc[tid] += t;
        __syncthreads();
    }
    aux[tid] = sc[tid] - own;
}

__global__ void k_scan3(unsigned* __restrict__ base, const unsigned* __restrict__ aux) {
    int i = blockIdx.x * 256 + threadIdx.x;
    base[i] += aux[i >> 10];
}

// scatter point ids into per-cell segments (base becomes end-offset)
__global__ void k_scatter(const int* __restrict__ cellid, unsigned* __restrict__ base,
                          unsigned* __restrict__ idxlist) {
    int idx = blockIdx.x * 256 + threadIdx.x;
    int cell = cellid[idx];
    unsigned pos = atomicAdd(&base[cell], 1u);
    idxlist[pos] = (unsigned)idx;
}

// one wave per cell: average its points, write bf16 grid (B,vox,C)
__global__ __launch_bounds__(256) void k_gather(
    const float* __restrict__ featsT, const unsigned* __restrict__ idxlist,
    const unsigned* __restrict__ base, const unsigned* __restrict__ cnt,
    __hip_bfloat16* __restrict__ xb) {
    int cell = blockIdx.x * 4 + (threadIdx.x >> 6);
    int lane = threadIdx.x & 63;
    unsigned n = cnt[cell];
    unsigned start = base[cell] - n;
    float acc = 0.f;
    unsigned pid = (n > 0) ? idxlist[start] : 0u;
    for (unsigned i = 0; i < n;) {
        unsigned p = pid;
        ++i;
        if (i < n) pid = idxlist[start + i];
        acc += featsT[((size_t)p << 6) + lane];
    }
    float inv = (n > 0) ? (1.0f / (float)n) : 0.f;
    xb[((size_t)cell << 6) + lane] = __float2bfloat16(acc * inv);
}

// conv_w (co,ci,kd,kh,kw) -> wb[tap][co][ci] bf16
__global__ void k_wb(const float* __restrict__ w, __hip_bfloat16* __restrict__ wb) {
    int i = blockIdx.x * 256 + threadIdx.x;              // CC*CC*27
    if (i >= CC * CC * 27) return;
    int tap = i % 27, t = i / 27;
    int ci = t & 63, co = t >> 6;
    wb[((size_t)(tap * 64 + co)) * 64 + ci] = __float2bfloat16(w[i]);
}

// implicit-GEMM conv: y[m, co] = sum_{tap,ci} xb[shift(m,tap), ci] * wb[tap][co][ci] + bias
__global__ __launch_bounds__(256) void k_conv_mfma(
    const ushort* __restrict__ xb, const ushort* __restrict__ wb,
    const float* __restrict__ bias, float* __restrict__ y,
    const ushort* __restrict__ zg) {
    int wid = threadIdx.x >> 6, lane = threadIdx.x & 63;
    int kg = lane >> 4, nl = lane & 15;
    int m = blockIdx.x * 64 + wid * 16 + nl;             // A-row voxel for this lane
    int b = m >> 15, d = (m >> 10) & 31, h = (m >> 5) & 31, w = m & 31;
    f32x4 acc[4];
    #pragma unroll
    for (int cb = 0; cb < 4; ++cb) acc[cb] = (f32x4){0.f, 0.f, 0.f, 0.f};

    #pragma unroll 1
    for (int tap = 0; tap < 27; ++tap) {
        int kd = tap / 9, kh = (tap / 3) % 3, kw = tap % 3;
        int dd = d + kd - 1, hh = h + kh - 1, ww = w + kw - 1;
        bool valid = ((unsigned)dd < 32u) && ((unsigned)hh < 32u) && ((unsigned)ww < 32u);
        const ushort* ab = valid
            ? xb + (((size_t)((b << 15) | (dd << 10) | (hh << 5) | ww)) << 6) + kg * 8
            : zg + kg * 8;
        const ushort* bbp = wb + tap * 4096 + nl * 64 + kg * 8;
        #pragma unroll
        for (int s = 0; s < 2; ++s) {
            bf16x8 af = *reinterpret_cast<const bf16x8*>(ab + s * 32);
            #pragma unroll
            for (int cb = 0; cb < 4; ++cb) {
                bf16x8 bf = *reinterpret_cast<const bf16x8*>(bbp + cb * 1024 + s * 32);
                acc[cb] = __builtin_amdgcn_mfma_f32_16x16x32_bf16(af, bf, acc[cb], 0, 0, 0);
            }
        }
    }

    int vbase = blockIdx.x * 64 + wid * 16 + kg * 4;
    #pragma unroll
    for (int cb = 0; cb < 4; ++cb) {
        int co = cb * 16 + nl;
        float bs = bias[co];
        #pragma unroll
        for (int r = 0; r < 4; ++r)
            y[(((size_t)(vbase + r)) << 6) + co] = acc[cb][r] + bs;
    }
}

// stats for channel-innermost layout (idx & 63 == channel)
__global__ void k_stats_ci(const float* __restrict__ x, float* __restrict__ stats) {
    int c = threadIdx.x & 63;
    float s = 0.f, s2 = 0.f;
    size_t stride = (size_t)gridDim.x * 256;
    for (size_t i = (size_t)blockIdx.x * 256 + threadIdx.x; i < (size_t)MTOT * CC; i += stride) {
        float v = x[i]; s += v; s2 += v * v;
    }
    __shared__ float red[512];
    red[threadIdx.x] = s; red[256 + threadIdx.x] = s2;
    __syncthreads();
    if (threadIdx.x < 64) {
        s  = red[threadIdx.x] + red[threadIdx.x + 64] + red[threadIdx.x + 128] + red[threadIdx.x + 192];
        s2 = red[256 + threadIdx.x] + red[256 + threadIdx.x + 64] + red[256 + threadIdx.x + 128] + red[256 + threadIdx.x + 192];
        atomicAdd(&stats[c], s);
        atomicAdd(&stats[64 + c], s2);
    }
}

__global__ void k_bn_ci_bf16(const float* __restrict__ y, const float* __restrict__ stats,
                             const float* __restrict__ g, const float* __restrict__ bb,
                             __hip_bfloat16* __restrict__ out) {
    size_t i = (size_t)blockIdx.x * 256 + threadIdx.x;
    int c = (int)(i & 63);
    float mu = stats[c] * (1.0f / MTOT);
    float var = stats[64 + c] * (1.0f / MTOT) - mu * mu;
    float v = (y[i] - mu) * rsqrtf(var + EPSV) * g[c] + bb[c];
    out[i] = __float2bfloat16(v > 0.f ? v : 0.1f * v);
}

__global__ void k_bn_ci_f32(const float* __restrict__ y, const float* __restrict__ stats,
                            const float* __restrict__ g, const float* __restrict__ bb,
                            float* __restrict__ out) {
    size_t i = (size_t)blockIdx.x * 256 + threadIdx.x;
    int c = (int)(i & 63);
    float mu = stats[c] * (1.0f / MTOT);
    float var = stats[64 + c] * (1.0f / MTOT) - mu * mu;
    float v = (y[i] - mu) * rsqrtf(var + EPSV) * g[c] + bb[c];
    out[i] = v > 0.f ? v : 0.1f * v;
}

// NDHWC -> NCDHW (64-vox x 64-ch tiles)
__global__ void k_transpose(const float* __restrict__ in, float* __restrict__ out) {
    __shared__ float t[64 * 65];
    size_t base = (size_t)blockIdx.x * 4096;
    int gv0 = blockIdx.x * 64;
    int b = gv0 >> 15;
    int vox0 = gv0 & 32767;
    #pragma unroll
    for (int k = 0; k < 16; ++k) {
        int idx = k * 256 + threadIdx.x;
        t[(idx >> 6) * 65 + (idx & 63)] = in[base + idx];
    }
    __syncthreads();
    #pragma unroll
    for (int k = 0; k < 16; ++k) {
        int idx = k * 256 + threadIdx.x;
        int ch = idx >> 6, voxl = idx & 63;
        out[((size_t)(b * 64 + ch)) * RV + vox0 + voxl] = t[voxl * 65 + ch];
    }
}

__global__ void k_mlp(const float* __restrict__ f, const float* __restrict__ w,
                      const float* __restrict__ bias, float* __restrict__ p) {
    __shared__ float wl[64 * 64];            // wl[ci*64+co]
    for (int k = threadIdx.x; k < 4096; k += 256) wl[k] = w[(k & 63) * 64 + (k >> 6)];
    __syncthreads();
    int b = blockIdx.x >> 7;
    int n0 = (blockIdx.x & 127) * 256 + threadIdx.x;
    float acc[64];
    #pragma unroll
    for (int co = 0; co < 64; ++co) acc[co] = 0.f;
    for (int ci = 0; ci < 64; ++ci) {
        float fv = f[((size_t)(b * 64 + ci)) * NPTS + n0];
        #pragma unroll
        for (int co = 0; co < 64; ++co) acc[co] += fv * wl[ci * 64 + co];
    }
    for (int co = 0; co < 64; ++co)
        p[((size_t)(b * 64 + co)) * NPTS + n0] = acc[co] + bias[co];
}

// stats for (B, C, N) layout: block per (b, c)
__global__ void k_stats_bcn(const float* __restrict__ x, float* __restrict__ stats) {
    int bc = blockIdx.x;                    // 512 blocks
    int c = bc & 63;
    const float* src = x + (size_t)bc * NPTS;
    float s = 0.f, s2 = 0.f;
    for (int i = threadIdx.x; i < NPTS; i += 256) { float v = src[i]; s += v; s2 += v * v; }
    __shared__ float red[512];
    red[threadIdx.x] = s; red[256 + threadIdx.x] = s2;
    __syncthreads();
    for (int w = 128; w > 0; w >>= 1) {
        if (threadIdx.x < w) {
            red[threadIdx.x] += red[threadIdx.x + w];
            red[256 + threadIdx.x] += red[256 + threadIdx.x + w];
        }
        __syncthreads();
    }
    if (threadIdx.x == 0) { atomicAdd(&stats[c], red[0]); atomicAdd(&stats[64 + c], red[256]); }
}

__global__ void k_final(float* __restrict__ p, const float* __restrict__ stats,
                        const float* __restrict__ g, const float* __restrict__ bb,
                        const float* __restrict__ vgrid, const float* __restrict__ norm) {
    int t = blockIdx.x;                      // 65536 blocks
    int ntile = t & 127; int bc = t >> 7;    // bc = b*64 + co
    int b = bc >> 6, co = bc & 63;
    int n = ntile * 256 + threadIdx.x;
    size_t pi = (size_t)bc * NPTS + n;

    float mu = stats[co] * (1.0f / MTOT);
    float var = stats[64 + co] * (1.0f / MTOT) - mu * mu;
    float pv = (p[pi] - mu) * rsqrtf(var + EPSV) * g[co] + bb[co];
    pv = pv > 0.f ? pv : 0.1f * pv;

    float n0 = norm[((size_t)(b * 3 + 0)) * NPTS + n];
    float n1 = norm[((size_t)(b * 3 + 1)) * NPTS + n];
    float n2 = norm[((size_t)(b * 3 + 2)) * NPTS + n];
    int lx = (int)floorf(n0), ly = (int)floorf(n1), lz = (int)floorf(n2);
    float fx = n0 - (float)lx, fy = n1 - (float)ly, fz = n2 - (float)lz;
    int hx = min(lx + 1, 31), hy = min(ly + 1, 31), hz = min(lz + 1, 31);
    const float* gb = vgrid + ((size_t)b << 15) * CC;

    float s = 0.f;
    #pragma unroll
    for (int dx = 0; dx < 2; ++dx) {
        int ix = dx ? hx : lx; float wx = dx ? fx : 1.f - fx;
        #pragma unroll
        for (int dy = 0; dy < 2; ++dy) {
            int iy = dy ? hy : ly; float wy = dy ? fy : 1.f - fy;
            #pragma unroll
            for (int dz = 0; dz < 2; ++dz) {
                int iz = dz ? hz : lz; float wz = dz ? fz : 1.f - fz;
                int idx = (ix * 32 + iy) * 32 + iz;
                s += gb[(size_t)idx * CC + co] * (wx * wy * wz);
            }
        }
    }
    p[pi] = s + pv;
}

extern "C" void kernel_launch(void* const* d_in, const int* in_sizes, int n_in,
                              void* d_out, int out_size, void* d_ws, size_t ws_size,
                              hipStream_t stream) {
    const float* features = (const float*)d_in[0];
    const float* coords   = (const float*)d_in[1];
    const float* conv1_w  = (const float*)d_in[2];
    const float* conv1_b  = (const float*)d_in[3];
    const float* bn1_g    = (const float*)d_in[4];
    const float* bn1_b    = (const float*)d_in[5];
    const float* conv2_w  = (const float*)d_in[6];
    const float* conv2_b  = (const float*)d_in[7];
    const float* bn2_g    = (const float*)d_in[8];
    const float* bn2_b    = (const float*)d_in[9];
    const float* mlp_w    = (const float*)d_in[10];
    const float* mlp_b    = (const float*)d_in[11];
    const float* bnp_g    = (const float*)d_in[12];
    const float* bnp_b    = (const float*)d_in[13];

    float* ws    = (float*)d_ws;
    float* bufA  = ws + OFF_BUFA;
    float* bufB  = ws + OFF_BUFB;
    __hip_bfloat16* xb  = (__hip_bfloat16*)(ws + OFF_BUFB);
    __hip_bfloat16* wb1 = (__hip_bfloat16*)(ws + OFF_WB1);
    __hip_bfloat16* wb2 = (__hip_bfloat16*)(ws + OFF_WB2);
    float* zg    = ws + OFF_ZG;
    unsigned* base    = (unsigned*)(ws + OFF_BASE);
    unsigned* idxlist = (unsigned*)(ws + OFF_IDX);
    unsigned* aux     = (unsigned*)(ws + OFF_AUX);
    int* cellid       = (int*)(ws + OFF_CELL);
    unsigned* cnt     = (unsigned*)(ws + OFF_CNT);
    float* mean  = ws + OFF_MEAN;
    float* nrm   = ws + OFF_NORM;
    float* s1    = ws + OFF_S1;
    float* s2    = ws + OFF_S2;
    float* sp    = ws + OFF_SP;

    float* outF  = (float*)d_out;                       // fused region, also p scratch
    float* outV  = (float*)d_out + (size_t)16777216;    // v region, also conv1 raw-y scratch

    hipMemsetAsync(cnt, 0, 262144 * 4, stream);
    hipMemsetAsync(zg, 0, 256, stream);
    hipMemsetAsync(s1, 0, 384 * 4, stream);             // s1,s2,sp contiguous

    k_coord_mean<<<24, 256, 0, stream>>>(coords, mean);
    k_transposeF<<<4096, 256, 0, stream>>>(features, bufA);
    k_cellid<<<1024, 256, 0, stream>>>(coords, mean, nrm, cellid, cnt);
    k_scan1<<<256, 256, 0, stream>>>(cnt, base, aux);
    k_scan2<<<1, 256, 0, stream>>>(aux);
    k_scan3<<<1024, 256, 0, stream>>>(base, aux);
    k_scatter<<<1024, 256, 0, stream>>>(cellid, base, idxlist);
    k_gather<<<65536, 256, 0, stream>>>(bufA, idxlist, base, cnt, xb);

    k_wb<<<432, 256, 0, stream>>>(conv1_w, wb1);
    k_wb<<<432, 256, 0, stream>>>(conv2_w, wb2);

    // conv1: xb -> outV (raw y1, f32 NDHWC)
    k_conv_mfma<<<4096, 256, 0, stream>>>((const ushort*)xb, (const ushort*)wb1, conv1_b, outV, (const ushort*)zg);
    k_stats_ci<<<2048, 256, 0, stream>>>(outV, s1);
    k_bn_ci_bf16<<<65536, 256, 0, stream>>>(outV, s1, bn1_g, bn1_b, xb);   // x2 bf16 -> xb

    // conv2: xb -> bufA (raw y2)
    k_conv_mfma<<<4096, 256, 0, stream>>>((const ushort*)xb, (const ushort*)wb2, conv2_b, bufA, (const ushort*)zg);
    k_stats_ci<<<2048, 256, 0, stream>>>(bufA, s2);
    k_bn_ci_f32<<<65536, 256, 0, stream>>>(bufA, s2, bn2_g, bn2_b, bufB);  // v ndhwc f32 -> bufB

    // v -> d_out (NCDHW)
    k_transpose<<<4096, 256, 0, stream>>>(bufB, outV);

    // point branch: p -> outF
    k_mlp<<<1024, 256, 0, stream>>>(features, mlp_w, mlp_b, outF);
    k_stats_bcn<<<512, 256, 0, stream>>>(outF, sp);

    // fuse (in-place over p)
    k_final<<<65536, 256, 0, stream>>>(outF, sp, bnp_g, bnp_b, bufB, nrm);
}

// Round 4
// 1457.517 us; speedup vs baseline: 21.3200x; 1.3351x over previous
//
#include <hip/hip_runtime.h>
#include <hip/hip_bf16.h>

#define BB 8
#define CC 64
#define NPTS 32768
#define RR 32
#define RV 32768            // 32^3
#define MTOT (BB*RV)        // 262144
#define EPSV 1e-4f

// ws float offsets
#define OFF_BUFA 0u               // 16777216 f32: featsT (B,N,C), later conv2 raw out
#define OFF_BUFB 16777216u        // 16777216 f32: [0:8388608] = xb bf16; later full = v ndhwc f32
#define OFF_WB1  25165824u        // 55296 float-slots = 110592 bf16
#define OFF_WB2  25221120u        // 55296
#define OFF_ZG   25276416u        // 64 floats zero guard
#define OFF_BASE 25276480u        // 262144 uint
#define OFF_IDX  25538624u        // 262144 uint
#define OFF_AUX  25800768u        // 256 uint
#define OFF_CELL 25801024u        // 262144 int
#define OFF_CNT  26063168u        // 262144 uint
#define OFF_MEAN 26325312u        // 24
#define OFF_NORM 33554432u        // 786432 (survives to k_final)
#define OFF_S1   34340864u        // 128
#define OFF_S2   34340992u        // 128
#define OFF_SP   34341120u        // 128

typedef __attribute__((ext_vector_type(8))) __bf16 bf16x8;
typedef __attribute__((ext_vector_type(8))) unsigned short u16x8;
typedef __attribute__((ext_vector_type(4))) float f32x4;

__global__ void k_coord_mean(const float* __restrict__ coords, float* __restrict__ mean) {
    int ba = blockIdx.x;                 // b*3 + axis, 24 blocks
    const float* src = coords + (size_t)ba * NPTS;
    float s = 0.f;
    for (int i = threadIdx.x; i < NPTS; i += 256) s += src[i];
    __shared__ float red[256];
    red[threadIdx.x] = s; __syncthreads();
    for (int w = 128; w > 0; w >>= 1) {
        if (threadIdx.x < w) red[threadIdx.x] += red[threadIdx.x + w];
        __syncthreads();
    }
    if (threadIdx.x == 0) mean[ba] = red[0] * (1.0f / NPTS);
}

// feats (B,C,N) -> featsT (B,N,C) f32
__global__ void k_transposeF(const float* __restrict__ in, float* __restrict__ out) {
    __shared__ float t[64 * 65];
    int b = blockIdx.x >> 9;
    int n0 = (blockIdx.x & 511) * 64;
    #pragma unroll
    for (int k = 0; k < 16; ++k) {
        int idx = k * 256 + threadIdx.x;
        int c = idx >> 6, nl = idx & 63;
        t[c * 65 + nl] = in[((size_t)(b * 64 + c)) * NPTS + n0 + nl];
    }
    __syncthreads();
    #pragma unroll
    for (int k = 0; k < 16; ++k) {
        int idx = k * 256 + threadIdx.x;
        int nl = idx >> 6, c = idx & 63;
        out[((size_t)((b << 15) + n0 + nl)) * 64 + c] = t[c * 65 + nl];
    }
}

// per point: norm, cell id, count
__global__ void k_cellid(const float* __restrict__ coords, const float* __restrict__ mean,
                         float* __restrict__ norm, int* __restrict__ cellid,
                         unsigned* __restrict__ cnt) {
    int idx = blockIdx.x * 256 + threadIdx.x;      // b*NPTS + n
    int b = idx >> 15, n = idx & (NPTS - 1);
    int flat = 0;
    #pragma unroll
    for (int a = 0; a < 3; ++a) {
        float c = coords[((size_t)(b * 3 + a)) * NPTS + n];
        float nm = (c - mean[b * 3 + a] + 1.0f) * (0.5f * RR);
        nm = fminf(fmaxf(nm, 0.0f), (float)(RR - 1));
        norm[((size_t)(b * 3 + a)) * NPTS + n] = nm;
        flat = flat * RR + (int)rintf(nm);
    }
    int cell = b * RV + flat;
    cellid[idx] = cell;
    atomicAdd(&cnt[cell], 1u);
}

// block-local exclusive scan: 256 blocks x 1024 cells
__global__ void k_scan1(const unsigned* __restrict__ cnt, unsigned* __restrict__ base,
                        unsigned* __restrict__ aux) {
    int tid = threadIdx.x;
    int c0 = blockIdx.x * 1024 + tid * 4;
    unsigned v0 = cnt[c0], v1 = cnt[c0 + 1], v2 = cnt[c0 + 2], v3 = cnt[c0 + 3];
    unsigned tot = v0 + v1 + v2 + v3;
    __shared__ unsigned sc[256];
    sc[tid] = tot; __syncthreads();
    for (int off = 1; off < 256; off <<= 1) {
        unsigned t = (tid >= off) ? sc[tid - off] : 0u;
        __syncthreads();
        sc[tid] += t;
        __syncthreads();
    }
    unsigned excl = sc[tid] - tot;
    base[c0] = excl;
    base[c0 + 1] = excl + v0;
    base[c0 + 2] = excl + v0 + v1;
    base[c0 + 3] = excl + v0 + v1 + v2;
    if (tid == 255) aux[blockIdx.x] = sc[255];
}

__global__ void k_scan2(unsigned* __restrict__ aux) {
    int tid = threadIdx.x;
    unsigned own = aux[tid];
    __shared__ unsigned sc[256];
    sc[tid] = own; __syncthreads();
    for (int off = 1; off < 256; off <<= 1) {
        unsigned t = (tid >= off) ? sc[tid - off] : 0u;
        __syncthreads();
        sc[tid] += t;
        __syncthreads();
    }
    aux[tid] = sc[tid] - own;
}

__global__ void k_scan3(unsigned* __restrict__ base, const unsigned* __restrict__ aux) {
    int i = blockIdx.x * 256 + threadIdx.x;
    base[i] += aux[i >> 10];
}

// scatter point ids into per-cell segments (base becomes end-offset)
__global__ void k_scatter(const int* __restrict__ cellid, unsigned* __restrict__ base,
                          unsigned* __restrict__ idxlist) {
    int idx = blockIdx.x * 256 + threadIdx.x;
    int cell = cellid[idx];
    unsigned pos = atomicAdd(&base[cell], 1u);
    idxlist[pos] = (unsigned)idx;
}

// one wave per cell: average its points, write bf16 grid (B,vox,C)
__global__ __launch_bounds__(256) void k_gather(
    const float* __restrict__ featsT, const unsigned* __restrict__ idxlist,
    const unsigned* __restrict__ base, const unsigned* __restrict__ cnt,
    __hip_bfloat16* __restrict__ xb) {
    int cell = blockIdx.x * 4 + (threadIdx.x >> 6);
    int lane = threadIdx.x & 63;
    unsigned n = cnt[cell];
    unsigned start = base[cell] - n;
    float acc = 0.f;
    unsigned pid = (n > 0) ? idxlist[start] : 0u;
    for (unsigned i = 0; i < n;) {
        unsigned p = pid;
        ++i;
        if (i < n) pid = idxlist[start + i];
        acc += featsT[((size_t)p << 6) + lane];
    }
    float inv = (n > 0) ? (1.0f / (float)n) : 0.f;
    xb[((size_t)cell << 6) + lane] = __float2bfloat16(acc * inv);
}

// conv_w (co,ci,kd,kh,kw) -> wb[tap][co][ci] bf16
__global__ void k_wb(const float* __restrict__ w, __hip_bfloat16* __restrict__ wb) {
    int i = blockIdx.x * 256 + threadIdx.x;              // CC*CC*27
    if (i >= CC * CC * 27) return;
    int tap = i % 27, t = i / 27;
    int ci = t & 63, co = t >> 6;
    wb[((size_t)(tap * 64 + co)) * 64 + ci] = __float2bfloat16(w[i]);
}

// implicit-GEMM conv with LDS-staged input halo.
// block: 4x4x8 output tile (128 voxels) x 64 co; halo 6x6x10 rows in LDS (zero-filled OOB).
// wave wid owns d-slice ld=wid: 32 voxels x 64 co = 2 m-frags x 4 cb-frags.
__global__ __launch_bounds__(256, 3) void k_conv_mfma(
    const ushort* __restrict__ xb, const ushort* __restrict__ wb,
    const float* __restrict__ bias, float* __restrict__ y) {
    __shared__ __align__(16) char sh[360 * 128];         // 46080 B
    int tid = threadIdx.x;
    int twi = blockIdx.x & 3, thi = (blockIdx.x >> 2) & 7;
    int tdi = (blockIdx.x >> 5) & 7, b = blockIdx.x >> 8;
    int d0 = tdi * 4, h0 = thi * 4, w0 = twi * 8;

    // stage halo: 360 rows x 8 chunks of 16B
    for (int c = tid; c < 2880; c += 256) {
        int row = c >> 3, off = c & 7;
        int dz = row / 60, rem = row - dz * 60;
        int hz = rem / 10, wz = rem - hz * 10;
        int gd = d0 - 1 + dz, gh = h0 - 1 + hz, gw = w0 - 1 + wz;
        u16x8 v = {0, 0, 0, 0, 0, 0, 0, 0};
        if ((unsigned)gd < 32u && (unsigned)gh < 32u && (unsigned)gw < 32u) {
            size_t srco = (((size_t)((b << 15) | (gd << 10) | (gh << 5) | gw)) << 6) + off * 8;
            v = *reinterpret_cast<const u16x8*>(xb + srco);
        }
        int la = ((row << 7) + (off << 4)) ^ ((row & 7) << 4);
        *reinterpret_cast<u16x8*>(sh + la) = v;
    }
    __syncthreads();

    int lane = tid & 63, wid = tid >> 6;
    int nl = lane & 15, kg = lane >> 4;
    int rowoff = (nl >> 3) * 10 + (nl & 7);              // lane's (lh,lw) row offset, mi=0

    f32x4 acc[2][4];
    #pragma unroll
    for (int mi = 0; mi < 2; ++mi)
        #pragma unroll
        for (int cb = 0; cb < 4; ++cb) acc[mi][cb] = (f32x4){0.f, 0.f, 0.f, 0.f};

    #pragma unroll 1
    for (int kd = 0; kd < 3; ++kd) {
        int dz6 = (wid + kd) * 6;
        #pragma unroll
        for (int kh = 0; kh < 3; ++kh) {
            #pragma unroll
            for (int kw = 0; kw < 3; ++kw) {
                int r0 = (dz6 + kh) * 10 + kw + rowoff;  // mi=0 row
                int r1 = r0 + 20;                        // mi=1 row (lh+2)
                int ba0 = ((r0 << 7) + (kg << 4)) ^ ((r0 & 7) << 4);
                int ba1 = ((r1 << 7) + (kg << 4)) ^ ((r1 & 7) << 4);
                bf16x8 a00 = *reinterpret_cast<const bf16x8*>(sh + (ba0));
                bf16x8 a01 = *reinterpret_cast<const bf16x8*>(sh + (ba0 ^ 64));
                bf16x8 a10 = *reinterpret_cast<const bf16x8*>(sh + (ba1));
                bf16x8 a11 = *reinterpret_cast<const bf16x8*>(sh + (ba1 ^ 64));
                int tap = (kd * 3 + kh) * 3 + kw;
                const ushort* wt = wb + tap * 4096 + nl * 64 + kg * 8;
                #pragma unroll
                for (int cb = 0; cb < 4; ++cb) {
                    bf16x8 b0 = *reinterpret_cast<const bf16x8*>(wt + cb * 1024);
                    bf16x8 b1 = *reinterpret_cast<const bf16x8*>(wt + cb * 1024 + 32);
                    acc[0][cb] = __builtin_amdgcn_mfma_f32_16x16x32_bf16(a00, b0, acc[0][cb], 0, 0, 0);
                    acc[0][cb] = __builtin_amdgcn_mfma_f32_16x16x32_bf16(a01, b1, acc[0][cb], 0, 0, 0);
                    acc[1][cb] = __builtin_amdgcn_mfma_f32_16x16x32_bf16(a10, b0, acc[1][cb], 0, 0, 0);
                    acc[1][cb] = __builtin_amdgcn_mfma_f32_16x16x32_bf16(a11, b1, acc[1][cb], 0, 0, 0);
                }
            }
        }
    }

    int d = d0 + wid;
    #pragma unroll
    for (int mi = 0; mi < 2; ++mi) {
        int h = h0 + mi * 2 + (kg >> 1);
        int w = w0 + (kg & 1) * 4;
        size_t vox = (size_t)((b << 15) | (d << 10) | (h << 5) | w);
        #pragma unroll
        for (int cb = 0; cb < 4; ++cb) {
            int co = cb * 16 + nl;
            float bs = bias[co];
            #pragma unroll
            for (int r = 0; r < 4; ++r)
                y[((vox + r) << 6) + co] = acc[mi][cb][r] + bs;
        }
    }
}

// stats for channel-innermost layout (idx & 63 == channel)
__global__ void k_stats_ci(const float* __restrict__ x, float* __restrict__ stats) {
    int c = threadIdx.x & 63;
    float s = 0.f, s2 = 0.f;
    size_t stride = (size_t)gridDim.x * 256;
    for (size_t i = (size_t)blockIdx.x * 256 + threadIdx.x; i < (size_t)MTOT * CC; i += stride) {
        float v = x[i]; s += v; s2 += v * v;
    }
    __shared__ float red[512];
    red[threadIdx.x] = s; red[256 + threadIdx.x] = s2;
    __syncthreads();
    if (threadIdx.x < 64) {
        s  = red[threadIdx.x] + red[threadIdx.x + 64] + red[threadIdx.x + 128] + red[threadIdx.x + 192];
        s2 = red[256 + threadIdx.x] + red[256 + threadIdx.x + 64] + red[256 + threadIdx.x + 128] + red[256 + threadIdx.x + 192];
        atomicAdd(&stats[c], s);
        atomicAdd(&stats[64 + c], s2);
    }
}

__global__ void k_bn_ci_bf16(const float* __restrict__ y, const float* __restrict__ stats,
                             const float* __restrict__ g, const float* __restrict__ bb,
                             __hip_bfloat16* __restrict__ out) {
    size_t i = (size_t)blockIdx.x * 256 + threadIdx.x;
    int c = (int)(i & 63);
    float mu = stats[c] * (1.0f / MTOT);
    float var = stats[64 + c] * (1.0f / MTOT) - mu * mu;
    float v = (y[i] - mu) * rsqrtf(var + EPSV) * g[c] + bb[c];
    out[i] = __float2bfloat16(v > 0.f ? v : 0.1f * v);
}

__global__ void k_bn_ci_f32(const float* __restrict__ y, const float* __restrict__ stats,
                            const float* __restrict__ g, const float* __restrict__ bb,
                            float* __restrict__ out) {
    size_t i = (size_t)blockIdx.x * 256 + threadIdx.x;
    int c = (int)(i & 63);
    float mu = stats[c] * (1.0f / MTOT);
    float var = stats[64 + c] * (1.0f / MTOT) - mu * mu;
    float v = (y[i] - mu) * rsqrtf(var + EPSV) * g[c] + bb[c];
    out[i] = v > 0.f ? v : 0.1f * v;
}

// NDHWC -> NCDHW (64-vox x 64-ch tiles)
__global__ void k_transpose(const float* __restrict__ in, float* __restrict__ out) {
    __shared__ float t[64 * 65];
    size_t base = (size_t)blockIdx.x * 4096;
    int gv0 = blockIdx.x * 64;
    int b = gv0 >> 15;
    int vox0 = gv0 & 32767;
    #pragma unroll
    for (int k = 0; k < 16; ++k) {
        int idx = k * 256 + threadIdx.x;
        t[(idx >> 6) * 65 + (idx & 63)] = in[base + idx];
    }
    __syncthreads();
    #pragma unroll
    for (int k = 0; k < 16; ++k) {
        int idx = k * 256 + threadIdx.x;
        int ch = idx >> 6, voxl = idx & 63;
        out[((size_t)(b * 64 + ch)) * RV + vox0 + voxl] = t[voxl * 65 + ch];
    }
}

__global__ void k_mlp(const float* __restrict__ f, const float* __restrict__ w,
                      const float* __restrict__ bias, float* __restrict__ p) {
    __shared__ float wl[64 * 64];            // wl[ci*64+co]
    for (int k = threadIdx.x; k < 4096; k += 256) wl[k] = w[(k & 63) * 64 + (k >> 6)];
    __syncthreads();
    int b = blockIdx.x >> 7;
    int n0 = (blockIdx.x & 127) * 256 + threadIdx.x;
    float acc[64];
    #pragma unroll
    for (int co = 0; co < 64; ++co) acc[co] = 0.f;
    for (int ci = 0; ci < 64; ++ci) {
        float fv = f[((size_t)(b * 64 + ci)) * NPTS + n0];
        #pragma unroll
        for (int co = 0; co < 64; ++co) acc[co] += fv * wl[ci * 64 + co];
    }
    for (int co = 0; co < 64; ++co)
        p[((size_t)(b * 64 + co)) * NPTS + n0] = acc[co] + bias[co];
}

// stats for (B, C, N) layout: block per (b, c)
__global__ void k_stats_bcn(const float* __restrict__ x, float* __restrict__ stats) {
    int bc = blockIdx.x;                    // 512 blocks
    int c = bc & 63;
    const float* src = x + (size_t)bc * NPTS;
    float s = 0.f, s2 = 0.f;
    for (int i = threadIdx.x; i < NPTS; i += 256) { float v = src[i]; s += v; s2 += v * v; }
    __shared__ float red[512];
    red[threadIdx.x] = s; red[256 + threadIdx.x] = s2;
    __syncthreads();
    for (int w = 128; w > 0; w >>= 1) {
        if (threadIdx.x < w) {
            red[threadIdx.x] += red[threadIdx.x + w];
            red[256 + threadIdx.x] += red[256 + threadIdx.x + w];
        }
        __syncthreads();
    }
    if (threadIdx.x == 0) { atomicAdd(&stats[c], red[0]); atomicAdd(&stats[64 + c], red[256]); }
}

__global__ void k_final(float* __restrict__ p, const float* __restrict__ stats,
                        const float* __restrict__ g, const float* __restrict__ bb,
                        const float* __restrict__ vgrid, const float* __restrict__ norm) {
    int t = blockIdx.x;                      // 65536 blocks
    int ntile = t & 127; int bc = t >> 7;    // bc = b*64 + co
    int b = bc >> 6, co = bc & 63;
    int n = ntile * 256 + threadIdx.x;
    size_t pi = (size_t)bc * NPTS + n;

    float mu = stats[co] * (1.0f / MTOT);
    float var = stats[64 + co] * (1.0f / MTOT) - mu * mu;
    float pv = (p[pi] - mu) * rsqrtf(var + EPSV) * g[co] + bb[co];
    pv = pv > 0.f ? pv : 0.1f * pv;

    float n0 = norm[((size_t)(b * 3 + 0)) * NPTS + n];
    float n1 = norm[((size_t)(b * 3 + 1)) * NPTS + n];
    float n2 = norm[((size_t)(b * 3 + 2)) * NPTS + n];
    int lx = (int)floorf(n0), ly = (int)floorf(n1), lz = (int)floorf(n2);
    float fx = n0 - (float)lx, fy = n1 - (float)ly, fz = n2 - (float)lz;
    int hx = min(lx + 1, 31), hy = min(ly + 1, 31), hz = min(lz + 1, 31);
    const float* gb = vgrid + ((size_t)b << 15) * CC;

    float s = 0.f;
    #pragma unroll
    for (int dx = 0; dx < 2; ++dx) {
        int ix = dx ? hx : lx; float wx = dx ? fx : 1.f - fx;
        #pragma unroll
        for (int dy = 0; dy < 2; ++dy) {
            int iy = dy ? hy : ly; float wy = dy ? fy : 1.f - fy;
            #pragma unroll
            for (int dz = 0; dz < 2; ++dz) {
                int iz = dz ? hz : lz; float wz = dz ? fz : 1.f - fz;
                int idx = (ix * 32 + iy) * 32 + iz;
                s += gb[(size_t)idx * CC + co] * (wx * wy * wz);
            }
        }
    }
    p[pi] = s + pv;
}

extern "C" void kernel_launch(void* const* d_in, const int* in_sizes, int n_in,
                              void* d_out, int out_size, void* d_ws, size_t ws_size,
                              hipStream_t stream) {
    const float* features = (const float*)d_in[0];
    const float* coords   = (const float*)d_in[1];
    const float* conv1_w  = (const float*)d_in[2];
    const float* conv1_b  = (const float*)d_in[3];
    const float* bn1_g    = (const float*)d_in[4];
    const float* bn1_b    = (const float*)d_in[5];
    const float* conv2_w  = (const float*)d_in[6];
    const float* conv2_b  = (const float*)d_in[7];
    const float* bn2_g    = (const float*)d_in[8];
    const float* bn2_b    = (const float*)d_in[9];
    const float* mlp_w    = (const float*)d_in[10];
    const float* mlp_b    = (const float*)d_in[11];
    const float* bnp_g    = (const float*)d_in[12];
    const float* bnp_b    = (const float*)d_in[13];

    float* ws    = (float*)d_ws;
    float* bufA  = ws + OFF_BUFA;
    float* bufB  = ws + OFF_BUFB;
    __hip_bfloat16* xb  = (__hip_bfloat16*)(ws + OFF_BUFB);
    __hip_bfloat16* wb1 = (__hip_bfloat16*)(ws + OFF_WB1);
    __hip_bfloat16* wb2 = (__hip_bfloat16*)(ws + OFF_WB2);
    float* zg    = ws + OFF_ZG;
    unsigned* base    = (unsigned*)(ws + OFF_BASE);
    unsigned* idxlist = (unsigned*)(ws + OFF_IDX);
    unsigned* aux     = (unsigned*)(ws + OFF_AUX);
    int* cellid       = (int*)(ws + OFF_CELL);
    unsigned* cnt     = (unsigned*)(ws + OFF_CNT);
    float* mean  = ws + OFF_MEAN;
    float* nrm   = ws + OFF_NORM;
    float* s1    = ws + OFF_S1;
    float* s2    = ws + OFF_S2;
    float* sp    = ws + OFF_SP;

    float* outF  = (float*)d_out;                       // fused region, also p scratch
    float* outV  = (float*)d_out + (size_t)16777216;    // v region, also conv1 raw-y scratch

    hipMemsetAsync(cnt, 0, 262144 * 4, stream);
    hipMemsetAsync(zg, 0, 256, stream);
    hipMemsetAsync(s1, 0, 384 * 4, stream);             // s1,s2,sp contiguous

    k_coord_mean<<<24, 256, 0, stream>>>(coords, mean);
    k_transposeF<<<4096, 256, 0, stream>>>(features, bufA);
    k_cellid<<<1024, 256, 0, stream>>>(coords, mean, nrm, cellid, cnt);
    k_scan1<<<256, 256, 0, stream>>>(cnt, base, aux);
    k_scan2<<<1, 256, 0, stream>>>(aux);
    k_scan3<<<1024, 256, 0, stream>>>(base, aux);
    k_scatter<<<1024, 256, 0, stream>>>(cellid, base, idxlist);
    k_gather<<<65536, 256, 0, stream>>>(bufA, idxlist, base, cnt, xb);

    k_wb<<<432, 256, 0, stream>>>(conv1_w, wb1);
    k_wb<<<432, 256, 0, stream>>>(conv2_w, wb2);

    // conv1: xb -> outV (raw y1, f32 NDHWC)
    k_conv_mfma<<<2048, 256, 0, stream>>>((const ushort*)xb, (const ushort*)wb1, conv1_b, outV);
    k_stats_ci<<<2048, 256, 0, stream>>>(outV, s1);
    k_bn_ci_bf16<<<65536, 256, 0, stream>>>(outV, s1, bn1_g, bn1_b, xb);   // x2 bf16 -> xb

    // conv2: xb -> bufA (raw y2)
    k_conv_mfma<<<2048, 256, 0, stream>>>((const ushort*)xb, (const ushort*)wb2, conv2_b, bufA);
    k_stats_ci<<<2048, 256, 0, stream>>>(bufA, s2);
    k_bn_ci_f32<<<65536, 256, 0, stream>>>(bufA, s2, bn2_g, bn2_b, bufB);  // v ndhwc f32 -> bufB

    // v -> d_out (NCDHW)
    k_transpose<<<4096, 256, 0, stream>>>(bufB, outV);

    // point branch: p -> outF
    k_mlp<<<1024, 256, 0, stream>>>(features, mlp_w, mlp_b, outF);
    k_stats_bcn<<<512, 256, 0, stream>>>(outF, sp);

    // fuse (in-place over p)
    k_final<<<65536, 256, 0, stream>>>(outF, sp, bnp_g, bnp_b, bufB, nrm);
}

// Round 5
// 1103.337 us; speedup vs baseline: 28.1639x; 1.3210x over previous
//
#include <hip/hip_runtime.h>
#include <hip/hip_bf16.h>

#define BB 8
#define CC 64
#define NPTS 32768
#define RR 32
#define RV 32768            // 32^3
#define MTOT (BB*RV)        // 262144
#define EPSV 1e-4f

// ws float offsets
#define OFF_BUFA 0u               // 16777216 f32: featsT (B,N,C), later conv2 raw out
#define OFF_BUFB 16777216u        // 16777216 f32: [0:8388608] = xb bf16; later full = v ndhwc f32
#define OFF_WB1  25165824u        // 55296 float-slots = 110592 bf16
#define OFF_WB2  25221120u        // 55296
#define OFF_ZG   25276416u        // 64 floats zero guard
#define OFF_BASE 25276480u        // 262144 uint
#define OFF_IDX  25538624u        // 262144 uint
#define OFF_AUX  25800768u        // 256 uint
#define OFF_CELL 25801024u        // 262144 int
#define OFF_CNT  26063168u        // 262144 uint
#define OFF_MEAN 26325312u        // 24
#define OFF_NORM 33554432u        // 786432 (survives to k_final)
#define OFF_S1   34340864u        // 128
#define OFF_S2   34340992u        // 128
#define OFF_SP   34341120u        // 128

typedef __attribute__((ext_vector_type(8))) __bf16 bf16x8;
typedef __attribute__((ext_vector_type(8))) unsigned short u16x8;
typedef __attribute__((ext_vector_type(4))) float f32x4;

__global__ void k_coord_mean(const float* __restrict__ coords, float* __restrict__ mean) {
    int ba = blockIdx.x;                 // b*3 + axis, 24 blocks
    const float* src = coords + (size_t)ba * NPTS;
    float s = 0.f;
    for (int i = threadIdx.x; i < NPTS; i += 256) s += src[i];
    __shared__ float red[256];
    red[threadIdx.x] = s; __syncthreads();
    for (int w = 128; w > 0; w >>= 1) {
        if (threadIdx.x < w) red[threadIdx.x] += red[threadIdx.x + w];
        __syncthreads();
    }
    if (threadIdx.x == 0) mean[ba] = red[0] * (1.0f / NPTS);
}

// feats (B,C,N) -> featsT (B,N,C) f32
__global__ void k_transposeF(const float* __restrict__ in, float* __restrict__ out) {
    __shared__ float t[64 * 65];
    int b = blockIdx.x >> 9;
    int n0 = (blockIdx.x & 511) * 64;
    #pragma unroll
    for (int k = 0; k < 16; ++k) {
        int idx = k * 256 + threadIdx.x;
        int c = idx >> 6, nl = idx & 63;
        t[c * 65 + nl] = in[((size_t)(b * 64 + c)) * NPTS + n0 + nl];
    }
    __syncthreads();
    #pragma unroll
    for (int k = 0; k < 16; ++k) {
        int idx = k * 256 + threadIdx.x;
        int nl = idx >> 6, c = idx & 63;
        out[((size_t)((b << 15) + n0 + nl)) * 64 + c] = t[c * 65 + nl];
    }
}

// per point: norm, cell id, count
__global__ void k_cellid(const float* __restrict__ coords, const float* __restrict__ mean,
                         float* __restrict__ norm, int* __restrict__ cellid,
                         unsigned* __restrict__ cnt) {
    int idx = blockIdx.x * 256 + threadIdx.x;      // b*NPTS + n
    int b = idx >> 15, n = idx & (NPTS - 1);
    int flat = 0;
    #pragma unroll
    for (int a = 0; a < 3; ++a) {
        float c = coords[((size_t)(b * 3 + a)) * NPTS + n];
        float nm = (c - mean[b * 3 + a] + 1.0f) * (0.5f * RR);
        nm = fminf(fmaxf(nm, 0.0f), (float)(RR - 1));
        norm[((size_t)(b * 3 + a)) * NPTS + n] = nm;
        flat = flat * RR + (int)rintf(nm);
    }
    int cell = b * RV + flat;
    cellid[idx] = cell;
    atomicAdd(&cnt[cell], 1u);
}

// block-local exclusive scan: 256 blocks x 1024 cells
__global__ void k_scan1(const unsigned* __restrict__ cnt, unsigned* __restrict__ base,
                        unsigned* __restrict__ aux) {
    int tid = threadIdx.x;
    int c0 = blockIdx.x * 1024 + tid * 4;
    unsigned v0 = cnt[c0], v1 = cnt[c0 + 1], v2 = cnt[c0 + 2], v3 = cnt[c0 + 3];
    unsigned tot = v0 + v1 + v2 + v3;
    __shared__ unsigned sc[256];
    sc[tid] = tot; __syncthreads();
    for (int off = 1; off < 256; off <<= 1) {
        unsigned t = (tid >= off) ? sc[tid - off] : 0u;
        __syncthreads();
        sc[tid] += t;
        __syncthreads();
    }
    unsigned excl = sc[tid] - tot;
    base[c0] = excl;
    base[c0 + 1] = excl + v0;
    base[c0 + 2] = excl + v0 + v1;
    base[c0 + 3] = excl + v0 + v1 + v2;
    if (tid == 255) aux[blockIdx.x] = sc[255];
}

__global__ void k_scan2(unsigned* __restrict__ aux) {
    int tid = threadIdx.x;
    unsigned own = aux[tid];
    __shared__ unsigned sc[256];
    sc[tid] = own; __syncthreads();
    for (int off = 1; off < 256; off <<= 1) {
        unsigned t = (tid >= off) ? sc[tid - off] : 0u;
        __syncthreads();
        sc[tid] += t;
        __syncthreads();
    }
    aux[tid] = sc[tid] - own;
}

__global__ void k_scan3(unsigned* __restrict__ base, const unsigned* __restrict__ aux) {
    int i = blockIdx.x * 256 + threadIdx.x;
    base[i] += aux[i >> 10];
}

// scatter point ids into per-cell segments (base becomes end-offset)
__global__ void k_scatter(const int* __restrict__ cellid, unsigned* __restrict__ base,
                          unsigned* __restrict__ idxlist) {
    int idx = blockIdx.x * 256 + threadIdx.x;
    int cell = cellid[idx];
    unsigned pos = atomicAdd(&base[cell], 1u);
    idxlist[pos] = (unsigned)idx;
}

// one wave per cell: average its points, write bf16 grid (B,vox,C)
__global__ __launch_bounds__(256) void k_gather(
    const float* __restrict__ featsT, const unsigned* __restrict__ idxlist,
    const unsigned* __restrict__ base, const unsigned* __restrict__ cnt,
    __hip_bfloat16* __restrict__ xb) {
    int cell = blockIdx.x * 4 + (threadIdx.x >> 6);
    int lane = threadIdx.x & 63;
    unsigned n = cnt[cell];
    unsigned start = base[cell] - n;
    float acc = 0.f;
    unsigned pid = (n > 0) ? idxlist[start] : 0u;
    for (unsigned i = 0; i < n;) {
        unsigned p = pid;
        ++i;
        if (i < n) pid = idxlist[start + i];
        acc += featsT[((size_t)p << 6) + lane];
    }
    float inv = (n > 0) ? (1.0f / (float)n) : 0.f;
    xb[((size_t)cell << 6) + lane] = __float2bfloat16(acc * inv);
}

// conv_w (co,ci,kd,kh,kw) -> wb[tap][co][ci] bf16
__global__ void k_wb(const float* __restrict__ w, __hip_bfloat16* __restrict__ wb) {
    int i = blockIdx.x * 256 + threadIdx.x;              // CC*CC*27
    if (i >= CC * CC * 27) return;
    int tap = i % 27, t = i / 27;
    int ci = t & 63, co = t >> 6;
    wb[((size_t)(tap * 64 + co)) * 64 + ci] = __float2bfloat16(w[i]);
}

// implicit-GEMM conv with LDS-staged input halo.
// block: 4x4x8 output tile (128 voxels) x 64 co; halo 6x6x10 rows in LDS (zero-filled OOB).
// wave wid owns d-slice ld=wid: 32 voxels x 64 co = 2 m-frags x 4 cb-frags.
__global__ __launch_bounds__(256, 3) void k_conv_mfma(
    const ushort* __restrict__ xb, const ushort* __restrict__ wb,
    const float* __restrict__ bias, float* __restrict__ y) {
    __shared__ __align__(16) char sh[360 * 128];         // 46080 B
    int tid = threadIdx.x;
    int twi = blockIdx.x & 3, thi = (blockIdx.x >> 2) & 7;
    int tdi = (blockIdx.x >> 5) & 7, b = blockIdx.x >> 8;
    int d0 = tdi * 4, h0 = thi * 4, w0 = twi * 8;

    // stage halo: 360 rows x 8 chunks of 16B
    for (int c = tid; c < 2880; c += 256) {
        int row = c >> 3, off = c & 7;
        int dz = row / 60, rem = row - dz * 60;
        int hz = rem / 10, wz = rem - hz * 10;
        int gd = d0 - 1 + dz, gh = h0 - 1 + hz, gw = w0 - 1 + wz;
        u16x8 v = {0, 0, 0, 0, 0, 0, 0, 0};
        if ((unsigned)gd < 32u && (unsigned)gh < 32u && (unsigned)gw < 32u) {
            size_t srco = (((size_t)((b << 15) | (gd << 10) | (gh << 5) | gw)) << 6) + off * 8;
            v = *reinterpret_cast<const u16x8*>(xb + srco);
        }
        int la = ((row << 7) + (off << 4)) ^ ((row & 7) << 4);
        *reinterpret_cast<u16x8*>(sh + la) = v;
    }
    __syncthreads();

    int lane = tid & 63, wid = tid >> 6;
    int nl = lane & 15, kg = lane >> 4;
    int rowoff = (nl >> 3) * 10 + (nl & 7);              // lane's (lh,lw) row offset, mi=0

    f32x4 acc[2][4];
    #pragma unroll
    for (int mi = 0; mi < 2; ++mi)
        #pragma unroll
        for (int cb = 0; cb < 4; ++cb) acc[mi][cb] = (f32x4){0.f, 0.f, 0.f, 0.f};

    #pragma unroll 1
    for (int kd = 0; kd < 3; ++kd) {
        int dz6 = (wid + kd) * 6;
        #pragma unroll
        for (int kh = 0; kh < 3; ++kh) {
            #pragma unroll
            for (int kw = 0; kw < 3; ++kw) {
                int r0 = (dz6 + kh) * 10 + kw + rowoff;  // mi=0 row
                int r1 = r0 + 20;                        // mi=1 row (lh+2)
                int ba0 = ((r0 << 7) + (kg << 4)) ^ ((r0 & 7) << 4);
                int ba1 = ((r1 << 7) + (kg << 4)) ^ ((r1 & 7) << 4);
                bf16x8 a00 = *reinterpret_cast<const bf16x8*>(sh + (ba0));
                bf16x8 a01 = *reinterpret_cast<const bf16x8*>(sh + (ba0 ^ 64));
                bf16x8 a10 = *reinterpret_cast<const bf16x8*>(sh + (ba1));
                bf16x8 a11 = *reinterpret_cast<const bf16x8*>(sh + (ba1 ^ 64));
                int tap = (kd * 3 + kh) * 3 + kw;
                const ushort* wt = wb + tap * 4096 + nl * 64 + kg * 8;
                #pragma unroll
                for (int cb = 0; cb < 4; ++cb) {
                    bf16x8 b0 = *reinterpret_cast<const bf16x8*>(wt + cb * 1024);
                    bf16x8 b1 = *reinterpret_cast<const bf16x8*>(wt + cb * 1024 + 32);
                    acc[0][cb] = __builtin_amdgcn_mfma_f32_16x16x32_bf16(a00, b0, acc[0][cb], 0, 0, 0);
                    acc[0][cb] = __builtin_amdgcn_mfma_f32_16x16x32_bf16(a01, b1, acc[0][cb], 0, 0, 0);
                    acc[1][cb] = __builtin_amdgcn_mfma_f32_16x16x32_bf16(a10, b0, acc[1][cb], 0, 0, 0);
                    acc[1][cb] = __builtin_amdgcn_mfma_f32_16x16x32_bf16(a11, b1, acc[1][cb], 0, 0, 0);
                }
            }
        }
    }

    int d = d0 + wid;
    #pragma unroll
    for (int mi = 0; mi < 2; ++mi) {
        int h = h0 + mi * 2 + (kg >> 1);
        int w = w0 + (kg & 1) * 4;
        size_t vox = (size_t)((b << 15) | (d << 10) | (h << 5) | w);
        #pragma unroll
        for (int cb = 0; cb < 4; ++cb) {
            int co = cb * 16 + nl;
            float bs = bias[co];
            #pragma unroll
            for (int r = 0; r < 4; ++r)
                y[((vox + r) << 6) + co] = acc[mi][cb][r] + bs;
        }
    }
}

// stats for channel-innermost layout (idx & 63 == channel)
__global__ void k_stats_ci(const float* __restrict__ x, float* __restrict__ stats) {
    int c = threadIdx.x & 63;
    float s = 0.f, s2 = 0.f;
    size_t stride = (size_t)gridDim.x * 256;
    for (size_t i = (size_t)blockIdx.x * 256 + threadIdx.x; i < (size_t)MTOT * CC; i += stride) {
        float v = x[i]; s += v; s2 += v * v;
    }
    __shared__ float red[512];
    red[threadIdx.x] = s; red[256 + threadIdx.x] = s2;
    __syncthreads();
    if (threadIdx.x < 64) {
        s  = red[threadIdx.x] + red[threadIdx.x + 64] + red[threadIdx.x + 128] + red[threadIdx.x + 192];
        s2 = red[256 + threadIdx.x] + red[256 + threadIdx.x + 64] + red[256 + threadIdx.x + 128] + red[256 + threadIdx.x + 192];
        atomicAdd(&stats[c], s);
        atomicAdd(&stats[64 + c], s2);
    }
}

__global__ void k_bn_ci_bf16(const float* __restrict__ y, const float* __restrict__ stats,
                             const float* __restrict__ g, const float* __restrict__ bb,
                             __hip_bfloat16* __restrict__ out) {
    size_t i = (size_t)blockIdx.x * 256 + threadIdx.x;
    int c = (int)(i & 63);
    float mu = stats[c] * (1.0f / MTOT);
    float var = stats[64 + c] * (1.0f / MTOT) - mu * mu;
    float v = (y[i] - mu) * rsqrtf(var + EPSV) * g[c] + bb[c];
    out[i] = __float2bfloat16(v > 0.f ? v : 0.1f * v);
}

__global__ void k_bn_ci_f32(const float* __restrict__ y, const float* __restrict__ stats,
                            const float* __restrict__ g, const float* __restrict__ bb,
                            float* __restrict__ out) {
    size_t i = (size_t)blockIdx.x * 256 + threadIdx.x;
    int c = (int)(i & 63);
    float mu = stats[c] * (1.0f / MTOT);
    float var = stats[64 + c] * (1.0f / MTOT) - mu * mu;
    float v = (y[i] - mu) * rsqrtf(var + EPSV) * g[c] + bb[c];
    out[i] = v > 0.f ? v : 0.1f * v;
}

// NDHWC -> NCDHW (64-vox x 64-ch tiles)
__global__ void k_transpose(const float* __restrict__ in, float* __restrict__ out) {
    __shared__ float t[64 * 65];
    size_t base = (size_t)blockIdx.x * 4096;
    int gv0 = blockIdx.x * 64;
    int b = gv0 >> 15;
    int vox0 = gv0 & 32767;
    #pragma unroll
    for (int k = 0; k < 16; ++k) {
        int idx = k * 256 + threadIdx.x;
        t[(idx >> 6) * 65 + (idx & 63)] = in[base + idx];
    }
    __syncthreads();
    #pragma unroll
    for (int k = 0; k < 16; ++k) {
        int idx = k * 256 + threadIdx.x;
        int ch = idx >> 6, voxl = idx & 63;
        out[((size_t)(b * 64 + ch)) * RV + vox0 + voxl] = t[voxl * 65 + ch];
    }
}

__global__ void k_mlp(const float* __restrict__ f, const float* __restrict__ w,
                      const float* __restrict__ bias, float* __restrict__ p) {
    __shared__ float wl[64 * 64];            // wl[ci*64+co]
    for (int k = threadIdx.x; k < 4096; k += 256) wl[k] = w[(k & 63) * 64 + (k >> 6)];
    __syncthreads();
    int b = blockIdx.x >> 7;
    int n0 = (blockIdx.x & 127) * 256 + threadIdx.x;
    float acc[64];
    #pragma unroll
    for (int co = 0; co < 64; ++co) acc[co] = 0.f;
    for (int ci = 0; ci < 64; ++ci) {
        float fv = f[((size_t)(b * 64 + ci)) * NPTS + n0];
        #pragma unroll
        for (int co = 0; co < 64; ++co) acc[co] += fv * wl[ci * 64 + co];
    }
    for (int co = 0; co < 64; ++co)
        p[((size_t)(b * 64 + co)) * NPTS + n0] = acc[co] + bias[co];
}

// stats for (B, C, N) layout: block per (b, c)
__global__ void k_stats_bcn(const float* __restrict__ x, float* __restrict__ stats) {
    int bc = blockIdx.x;                    // 512 blocks
    int c = bc & 63;
    const float* src = x + (size_t)bc * NPTS;
    float s = 0.f, s2 = 0.f;
    for (int i = threadIdx.x; i < NPTS; i += 256) { float v = src[i]; s += v; s2 += v * v; }
    __shared__ float red[512];
    red[threadIdx.x] = s; red[256 + threadIdx.x] = s2;
    __syncthreads();
    for (int w = 128; w > 0; w >>= 1) {
        if (threadIdx.x < w) {
            red[threadIdx.x] += red[threadIdx.x + w];
            red[256 + threadIdx.x] += red[256 + threadIdx.x + w];
        }
        __syncthreads();
    }
    if (threadIdx.x == 0) { atomicAdd(&stats[c], red[0]); atomicAdd(&stats[64 + c], red[256]); }
}

// fused BN(p)+leaky + trilinear devoxelize + add.
// block = 64 points x 64 channels; phase 1: lane=channel, coalesced 256B corner rows -> LDS;
// phase 2: per-wave co fixed, coalesced p read/modify/write along n.
__global__ __launch_bounds__(256) void k_final(
    float* __restrict__ p, const float* __restrict__ stats,
    const float* __restrict__ g, const float* __restrict__ bb,
    const float* __restrict__ vgrid, const float* __restrict__ norm) {
    __shared__ float smp[64 * 65];
    int b = blockIdx.x >> 9;                 // 512 tiles per batch
    int n0 = (blockIdx.x & 511) * 64;
    int wid = threadIdx.x >> 6, lane = threadIdx.x & 63;
    const float* gb = vgrid + (((size_t)b) << 15) * CC;
    const float* nrm0 = norm + ((size_t)(b * 3)) * NPTS;

    #pragma unroll 2
    for (int i = 0; i < 16; ++i) {
        int pl = wid * 16 + i;
        int n = n0 + pl;
        float v0 = nrm0[n];
        float v1 = nrm0[NPTS + n];
        float v2 = nrm0[2 * NPTS + n];
        int lx = (int)floorf(v0), ly = (int)floorf(v1), lz = (int)floorf(v2);
        float fx = v0 - (float)lx, fy = v1 - (float)ly, fz = v2 - (float)lz;
        int hx = min(lx + 1, 31), hy = min(ly + 1, 31), hz = min(lz + 1, 31);
        float gx = 1.f - fx, gy = 1.f - fy, gz = 1.f - fz;

        int i000 = ((lx * 32 + ly) * 32 + lz) << 6;
        int i001 = ((lx * 32 + ly) * 32 + hz) << 6;
        int i010 = ((lx * 32 + hy) * 32 + lz) << 6;
        int i011 = ((lx * 32 + hy) * 32 + hz) << 6;
        int i100 = ((hx * 32 + ly) * 32 + lz) << 6;
        int i101 = ((hx * 32 + ly) * 32 + hz) << 6;
        int i110 = ((hx * 32 + hy) * 32 + lz) << 6;
        int i111 = ((hx * 32 + hy) * 32 + hz) << 6;

        float s = gb[i000 + lane] * (gx * gy * gz)
                + gb[i001 + lane] * (gx * gy * fz)
                + gb[i010 + lane] * (gx * fy * gz)
                + gb[i011 + lane] * (gx * fy * fz)
                + gb[i100 + lane] * (fx * gy * gz)
                + gb[i101 + lane] * (fx * gy * fz)
                + gb[i110 + lane] * (fx * fy * gz)
                + gb[i111 + lane] * (fx * fy * fz);
        smp[pl * 65 + lane] = s;
    }
    __syncthreads();

    #pragma unroll 4
    for (int i = 0; i < 16; ++i) {
        int co = i * 4 + wid;
        size_t pi = ((size_t)(b * 64 + co)) * NPTS + n0 + lane;
        float mu = stats[co] * (1.0f / MTOT);
        float var = stats[64 + co] * (1.0f / MTOT) - mu * mu;
        float pv = (p[pi] - mu) * rsqrtf(var + EPSV) * g[co] + bb[co];
        pv = pv > 0.f ? pv : 0.1f * pv;
        p[pi] = smp[lane * 65 + co] + pv;
    }
}

extern "C" void kernel_launch(void* const* d_in, const int* in_sizes, int n_in,
                              void* d_out, int out_size, void* d_ws, size_t ws_size,
                              hipStream_t stream) {
    const float* features = (const float*)d_in[0];
    const float* coords   = (const float*)d_in[1];
    const float* conv1_w  = (const float*)d_in[2];
    const float* conv1_b  = (const float*)d_in[3];
    const float* bn1_g    = (const float*)d_in[4];
    const float* bn1_b    = (const float*)d_in[5];
    const float* conv2_w  = (const float*)d_in[6];
    const float* conv2_b  = (const float*)d_in[7];
    const float* bn2_g    = (const float*)d_in[8];
    const float* bn2_b    = (const float*)d_in[9];
    const float* mlp_w    = (const float*)d_in[10];
    const float* mlp_b    = (const float*)d_in[11];
    const float* bnp_g    = (const float*)d_in[12];
    const float* bnp_b    = (const float*)d_in[13];

    float* ws    = (float*)d_ws;
    float* bufA  = ws + OFF_BUFA;
    float* bufB  = ws + OFF_BUFB;
    __hip_bfloat16* xb  = (__hip_bfloat16*)(ws + OFF_BUFB);
    __hip_bfloat16* wb1 = (__hip_bfloat16*)(ws + OFF_WB1);
    __hip_bfloat16* wb2 = (__hip_bfloat16*)(ws + OFF_WB2);
    float* zg    = ws + OFF_ZG;
    unsigned* base    = (unsigned*)(ws + OFF_BASE);
    unsigned* idxlist = (unsigned*)(ws + OFF_IDX);
    unsigned* aux     = (unsigned*)(ws + OFF_AUX);
    int* cellid       = (int*)(ws + OFF_CELL);
    unsigned* cnt     = (unsigned*)(ws + OFF_CNT);
    float* mean  = ws + OFF_MEAN;
    float* nrm   = ws + OFF_NORM;
    float* s1    = ws + OFF_S1;
    float* s2    = ws + OFF_S2;
    float* sp    = ws + OFF_SP;

    float* outF  = (float*)d_out;                       // fused region, also p scratch
    float* outV  = (float*)d_out + (size_t)16777216;    // v region, also conv1 raw-y scratch

    hipMemsetAsync(cnt, 0, 262144 * 4, stream);
    hipMemsetAsync(zg, 0, 256, stream);
    hipMemsetAsync(s1, 0, 384 * 4, stream);             // s1,s2,sp contiguous

    k_coord_mean<<<24, 256, 0, stream>>>(coords, mean);
    k_transposeF<<<4096, 256, 0, stream>>>(features, bufA);
    k_cellid<<<1024, 256, 0, stream>>>(coords, mean, nrm, cellid, cnt);
    k_scan1<<<256, 256, 0, stream>>>(cnt, base, aux);
    k_scan2<<<1, 256, 0, stream>>>(aux);
    k_scan3<<<1024, 256, 0, stream>>>(base, aux);
    k_scatter<<<1024, 256, 0, stream>>>(cellid, base, idxlist);
    k_gather<<<65536, 256, 0, stream>>>(bufA, idxlist, base, cnt, xb);

    k_wb<<<432, 256, 0, stream>>>(conv1_w, wb1);
    k_wb<<<432, 256, 0, stream>>>(conv2_w, wb2);

    // conv1: xb -> outV (raw y1, f32 NDHWC)
    k_conv_mfma<<<2048, 256, 0, stream>>>((const ushort*)xb, (const ushort*)wb1, conv1_b, outV);
    k_stats_ci<<<2048, 256, 0, stream>>>(outV, s1);
    k_bn_ci_bf16<<<65536, 256, 0, stream>>>(outV, s1, bn1_g, bn1_b, xb);   // x2 bf16 -> xb

    // conv2: xb -> bufA (raw y2)
    k_conv_mfma<<<2048, 256, 0, stream>>>((const ushort*)xb, (const ushort*)wb2, conv2_b, bufA);
    k_stats_ci<<<2048, 256, 0, stream>>>(bufA, s2);
    k_bn_ci_f32<<<65536, 256, 0, stream>>>(bufA, s2, bn2_g, bn2_b, bufB);  // v ndhwc f32 -> bufB

    // v -> d_out (NCDHW)
    k_transpose<<<4096, 256, 0, stream>>>(bufB, outV);

    // point branch: p -> outF
    k_mlp<<<1024, 256, 0, stream>>>(features, mlp_w, mlp_b, outF);
    k_stats_bcn<<<512, 256, 0, stream>>>(outF, sp);

    // fuse (in-place over p)
    k_final<<<4096, 256, 0, stream>>>(outF, sp, bnp_g, bnp_b, bufB, nrm);
}

// Round 6
// 1076.353 us; speedup vs baseline: 28.8699x; 1.0251x over previous
//
#include <hip/hip_runtime.h>
#include <hip/hip_bf16.h>

#define BB 8
#define CC 64
#define NPTS 32768
#define RR 32
#define RV 32768            // 32^3
#define MTOT (BB*RV)        // 262144
#define EPSV 1e-4f

// ws float offsets
#define OFF_BUFA 0u               // 16777216 f32: featsT (B,N,C), later conv2 raw out
#define OFF_BUFB 16777216u        // 16777216 f32: [0:8388608] = xb bf16; later full = v ndhwc f32
#define OFF_WB1  25165824u        // 55296 float-slots = 110592 bf16
#define OFF_WB2  25221120u        // 55296
#define OFF_ZG   25276416u        // 64 floats zero guard
#define OFF_BASE 25276480u        // 262144 uint
#define OFF_IDX  25538624u        // 262144 uint
#define OFF_AUX  25800768u        // 256 uint
#define OFF_CELL 25801024u        // 262144 int
#define OFF_CNT  26063168u        // 262144 uint
#define OFF_MEAN 26325312u        // 24
#define OFF_NORM 33554432u        // 786432 (survives to k_final)
#define OFF_S1   34340864u        // 128
#define OFF_S2   34340992u        // 128
#define OFF_SP   34341120u        // 128

typedef __attribute__((ext_vector_type(8))) __bf16 bf16x8;
typedef __attribute__((ext_vector_type(8))) unsigned short u16x8;
typedef __attribute__((ext_vector_type(4))) float f32x4;

__global__ void k_coord_mean(const float* __restrict__ coords, float* __restrict__ mean) {
    int ba = blockIdx.x;                 // b*3 + axis, 24 blocks
    const float* src = coords + (size_t)ba * NPTS;
    float s = 0.f;
    for (int i = threadIdx.x; i < NPTS; i += 256) s += src[i];
    __shared__ float red[256];
    red[threadIdx.x] = s; __syncthreads();
    for (int w = 128; w > 0; w >>= 1) {
        if (threadIdx.x < w) red[threadIdx.x] += red[threadIdx.x + w];
        __syncthreads();
    }
    if (threadIdx.x == 0) mean[ba] = red[0] * (1.0f / NPTS);
}

// feats (B,C,N) -> featsT (B,N,C) f32
__global__ void k_transposeF(const float* __restrict__ in, float* __restrict__ out) {
    __shared__ float t[64 * 65];
    int b = blockIdx.x >> 9;
    int n0 = (blockIdx.x & 511) * 64;
    #pragma unroll
    for (int k = 0; k < 16; ++k) {
        int idx = k * 256 + threadIdx.x;
        int c = idx >> 6, nl = idx & 63;
        t[c * 65 + nl] = in[((size_t)(b * 64 + c)) * NPTS + n0 + nl];
    }
    __syncthreads();
    #pragma unroll
    for (int k = 0; k < 16; ++k) {
        int idx = k * 256 + threadIdx.x;
        int nl = idx >> 6, c = idx & 63;
        out[((size_t)((b << 15) + n0 + nl)) * 64 + c] = t[c * 65 + nl];
    }
}

// per point: norm, cell id, count
__global__ void k_cellid(const float* __restrict__ coords, const float* __restrict__ mean,
                         float* __restrict__ norm, int* __restrict__ cellid,
                         unsigned* __restrict__ cnt) {
    int idx = blockIdx.x * 256 + threadIdx.x;      // b*NPTS + n
    int b = idx >> 15, n = idx & (NPTS - 1);
    int flat = 0;
    #pragma unroll
    for (int a = 0; a < 3; ++a) {
        float c = coords[((size_t)(b * 3 + a)) * NPTS + n];
        float nm = (c - mean[b * 3 + a] + 1.0f) * (0.5f * RR);
        nm = fminf(fmaxf(nm, 0.0f), (float)(RR - 1));
        norm[((size_t)(b * 3 + a)) * NPTS + n] = nm;
        flat = flat * RR + (int)rintf(nm);
    }
    int cell = b * RV + flat;
    cellid[idx] = cell;
    atomicAdd(&cnt[cell], 1u);
}

// block-local exclusive scan: 256 blocks x 1024 cells
__global__ void k_scan1(const unsigned* __restrict__ cnt, unsigned* __restrict__ base,
                        unsigned* __restrict__ aux) {
    int tid = threadIdx.x;
    int c0 = blockIdx.x * 1024 + tid * 4;
    unsigned v0 = cnt[c0], v1 = cnt[c0 + 1], v2 = cnt[c0 + 2], v3 = cnt[c0 + 3];
    unsigned tot = v0 + v1 + v2 + v3;
    __shared__ unsigned sc[256];
    sc[tid] = tot; __syncthreads();
    for (int off = 1; off < 256; off <<= 1) {
        unsigned t = (tid >= off) ? sc[tid - off] : 0u;
        __syncthreads();
        sc[tid] += t;
        __syncthreads();
    }
    unsigned excl = sc[tid] - tot;
    base[c0] = excl;
    base[c0 + 1] = excl + v0;
    base[c0 + 2] = excl + v0 + v1;
    base[c0 + 3] = excl + v0 + v1 + v2;
    if (tid == 255) aux[blockIdx.x] = sc[255];
}

__global__ void k_scan2(unsigned* __restrict__ aux) {
    int tid = threadIdx.x;
    unsigned own = aux[tid];
    __shared__ unsigned sc[256];
    sc[tid] = own; __syncthreads();
    for (int off = 1; off < 256; off <<= 1) {
        unsigned t = (tid >= off) ? sc[tid - off] : 0u;
        __syncthreads();
        sc[tid] += t;
        __syncthreads();
    }
    aux[tid] = sc[tid] - own;
}

__global__ void k_scan3(unsigned* __restrict__ base, const unsigned* __restrict__ aux) {
    int i = blockIdx.x * 256 + threadIdx.x;
    base[i] += aux[i >> 10];
}

// scatter point ids into per-cell segments (base becomes end-offset)
__global__ void k_scatter(const int* __restrict__ cellid, unsigned* __restrict__ base,
                          unsigned* __restrict__ idxlist) {
    int idx = blockIdx.x * 256 + threadIdx.x;
    int cell = cellid[idx];
    unsigned pos = atomicAdd(&base[cell], 1u);
    idxlist[pos] = (unsigned)idx;
}

// one wave per cell: average its points, write bf16 grid (B,vox,C)
__global__ __launch_bounds__(256) void k_gather(
    const float* __restrict__ featsT, const unsigned* __restrict__ idxlist,
    const unsigned* __restrict__ base, const unsigned* __restrict__ cnt,
    __hip_bfloat16* __restrict__ xb) {
    int cell = blockIdx.x * 4 + (threadIdx.x >> 6);
    int lane = threadIdx.x & 63;
    unsigned n = cnt[cell];
    unsigned start = base[cell] - n;
    float acc = 0.f;
    unsigned pid = (n > 0) ? idxlist[start] : 0u;
    for (unsigned i = 0; i < n;) {
        unsigned p = pid;
        ++i;
        if (i < n) pid = idxlist[start + i];
        acc += featsT[((size_t)p << 6) + lane];
    }
    float inv = (n > 0) ? (1.0f / (float)n) : 0.f;
    xb[((size_t)cell << 6) + lane] = __float2bfloat16(acc * inv);
}

// conv_w (co,ci,kd,kh,kw) -> wb[tap][co][ci] bf16
__global__ void k_wb(const float* __restrict__ w, __hip_bfloat16* __restrict__ wb) {
    int i = blockIdx.x * 256 + threadIdx.x;              // CC*CC*27
    if (i >= CC * CC * 27) return;
    int tap = i % 27, t = i / 27;
    int ci = t & 63, co = t >> 6;
    wb[((size_t)(tap * 64 + co)) * 64 + ci] = __float2bfloat16(w[i]);
}

// implicit-GEMM conv with LDS-staged input halo + full 27-tap unroll with
// one-tap-ahead register double-buffer of A (LDS) and B (global) fragments.
__global__ __launch_bounds__(256, 3) void k_conv_mfma(
    const ushort* __restrict__ xb, const ushort* __restrict__ wb,
    const float* __restrict__ bias, float* __restrict__ y) {
    __shared__ __align__(16) char sh[360 * 128];         // 46080 B
    int tid = threadIdx.x;
    int twi = blockIdx.x & 3, thi = (blockIdx.x >> 2) & 7;
    int tdi = (blockIdx.x >> 5) & 7, b = blockIdx.x >> 8;
    int d0 = tdi * 4, h0 = thi * 4, w0 = twi * 8;

    // stage halo: 360 rows x 8 chunks of 16B
    for (int c = tid; c < 2880; c += 256) {
        int row = c >> 3, off = c & 7;
        int dz = row / 60, rem = row - dz * 60;
        int hz = rem / 10, wz = rem - hz * 10;
        int gd = d0 - 1 + dz, gh = h0 - 1 + hz, gw = w0 - 1 + wz;
        u16x8 v = {0, 0, 0, 0, 0, 0, 0, 0};
        if ((unsigned)gd < 32u && (unsigned)gh < 32u && (unsigned)gw < 32u) {
            size_t srco = (((size_t)((b << 15) | (gd << 10) | (gh << 5) | gw)) << 6) + off * 8;
            v = *reinterpret_cast<const u16x8*>(xb + srco);
        }
        int la = ((row << 7) + (off << 4)) ^ ((row & 7) << 4);
        *reinterpret_cast<u16x8*>(sh + la) = v;
    }
    __syncthreads();

    int lane = tid & 63, wid = tid >> 6;
    int nl = lane & 15, kg = lane >> 4;
    int rowoff = (nl >> 3) * 10 + (nl & 7);
    int rbase = wid * 60 + rowoff;                       // + kd*60 + kh*10 + kw = tap row
    const ushort* wbase = wb + nl * 64 + kg * 8;

    f32x4 acc[2][4];
    #pragma unroll
    for (int mi = 0; mi < 2; ++mi)
        #pragma unroll
        for (int cb = 0; cb < 4; ++cb) acc[mi][cb] = (f32x4){0.f, 0.f, 0.f, 0.f};

    bf16x8 Af[2][4];      // [parity][a00,a01,a10,a11]
    bf16x8 Bf[2][8];      // [parity][cb*2+ks]

    auto loadtap = [&](int t, int par) {
        int kd = t / 9, kh = (t / 3) % 3, kw = t % 3;    // compile-time under full unroll
        const ushort* wt = wbase + t * 4096;
        #pragma unroll
        for (int cb = 0; cb < 4; ++cb) {
            Bf[par][cb * 2 + 0] = *reinterpret_cast<const bf16x8*>(wt + cb * 1024);
            Bf[par][cb * 2 + 1] = *reinterpret_cast<const bf16x8*>(wt + cb * 1024 + 32);
        }
        int r0 = rbase + kd * 60 + kh * 10 + kw;
        int r1 = r0 + 20;
        int ba0 = ((r0 << 7) + (kg << 4)) ^ ((r0 & 7) << 4);
        int ba1 = ((r1 << 7) + (kg << 4)) ^ ((r1 & 7) << 4);
        Af[par][0] = *reinterpret_cast<const bf16x8*>(sh + ba0);
        Af[par][1] = *reinterpret_cast<const bf16x8*>(sh + (ba0 ^ 64));
        Af[par][2] = *reinterpret_cast<const bf16x8*>(sh + ba1);
        Af[par][3] = *reinterpret_cast<const bf16x8*>(sh + (ba1 ^ 64));
    };

    loadtap(0, 0);
    #pragma unroll
    for (int t = 0; t < 27; ++t) {
        int cur = t & 1;
        if (t < 26) loadtap(t + 1, cur ^ 1);             // issue next tap's loads first
        #pragma unroll
        for (int cb = 0; cb < 4; ++cb) {
            acc[0][cb] = __builtin_amdgcn_mfma_f32_16x16x32_bf16(Af[cur][0], Bf[cur][cb * 2 + 0], acc[0][cb], 0, 0, 0);
            acc[0][cb] = __builtin_amdgcn_mfma_f32_16x16x32_bf16(Af[cur][1], Bf[cur][cb * 2 + 1], acc[0][cb], 0, 0, 0);
            acc[1][cb] = __builtin_amdgcn_mfma_f32_16x16x32_bf16(Af[cur][2], Bf[cur][cb * 2 + 0], acc[1][cb], 0, 0, 0);
            acc[1][cb] = __builtin_amdgcn_mfma_f32_16x16x32_bf16(Af[cur][3], Bf[cur][cb * 2 + 1], acc[1][cb], 0, 0, 0);
        }
    }

    int d = d0 + wid;
    #pragma unroll
    for (int mi = 0; mi < 2; ++mi) {
        int h = h0 + mi * 2 + (kg >> 1);
        int w = w0 + (kg & 1) * 4;
        size_t vox = (size_t)((b << 15) | (d << 10) | (h << 5) | w);
        #pragma unroll
        for (int cb = 0; cb < 4; ++cb) {
            int co = cb * 16 + nl;
            float bs = bias[co];
            #pragma unroll
            for (int r = 0; r < 4; ++r)
                y[((vox + r) << 6) + co] = acc[mi][cb][r] + bs;
        }
    }
}

// stats for channel-innermost layout (idx & 63 == channel)
__global__ void k_stats_ci(const float* __restrict__ x, float* __restrict__ stats) {
    int c = threadIdx.x & 63;
    float s = 0.f, s2 = 0.f;
    size_t stride = (size_t)gridDim.x * 256;
    for (size_t i = (size_t)blockIdx.x * 256 + threadIdx.x; i < (size_t)MTOT * CC; i += stride) {
        float v = x[i]; s += v; s2 += v * v;
    }
    __shared__ float red[512];
    red[threadIdx.x] = s; red[256 + threadIdx.x] = s2;
    __syncthreads();
    if (threadIdx.x < 64) {
        s  = red[threadIdx.x] + red[threadIdx.x + 64] + red[threadIdx.x + 128] + red[threadIdx.x + 192];
        s2 = red[256 + threadIdx.x] + red[256 + threadIdx.x + 64] + red[256 + threadIdx.x + 128] + red[256 + threadIdx.x + 192];
        atomicAdd(&stats[c], s);
        atomicAdd(&stats[64 + c], s2);
    }
}

__global__ void k_bn_ci_bf16(const float* __restrict__ y, const float* __restrict__ stats,
                             const float* __restrict__ g, const float* __restrict__ bb,
                             __hip_bfloat16* __restrict__ out) {
    size_t i = (size_t)blockIdx.x * 256 + threadIdx.x;
    int c = (int)(i & 63);
    float mu = stats[c] * (1.0f / MTOT);
    float var = stats[64 + c] * (1.0f / MTOT) - mu * mu;
    float v = (y[i] - mu) * rsqrtf(var + EPSV) * g[c] + bb[c];
    out[i] = __float2bfloat16(v > 0.f ? v : 0.1f * v);
}

__global__ void k_bn_ci_f32(const float* __restrict__ y, const float* __restrict__ stats,
                            const float* __restrict__ g, const float* __restrict__ bb,
                            float* __restrict__ out) {
    size_t i = (size_t)blockIdx.x * 256 + threadIdx.x;
    int c = (int)(i & 63);
    float mu = stats[c] * (1.0f / MTOT);
    float var = stats[64 + c] * (1.0f / MTOT) - mu * mu;
    float v = (y[i] - mu) * rsqrtf(var + EPSV) * g[c] + bb[c];
    out[i] = v > 0.f ? v : 0.1f * v;
}

// NDHWC -> NCDHW (64-vox x 64-ch tiles)
__global__ void k_transpose(const float* __restrict__ in, float* __restrict__ out) {
    __shared__ float t[64 * 65];
    size_t base = (size_t)blockIdx.x * 4096;
    int gv0 = blockIdx.x * 64;
    int b = gv0 >> 15;
    int vox0 = gv0 & 32767;
    #pragma unroll
    for (int k = 0; k < 16; ++k) {
        int idx = k * 256 + threadIdx.x;
        t[(idx >> 6) * 65 + (idx & 63)] = in[base + idx];
    }
    __syncthreads();
    #pragma unroll
    for (int k = 0; k < 16; ++k) {
        int idx = k * 256 + threadIdx.x;
        int ch = idx >> 6, voxl = idx & 63;
        out[((size_t)(b * 64 + ch)) * RV + vox0 + voxl] = t[voxl * 65 + ch];
    }
}

__global__ void k_mlp(const float* __restrict__ f, const float* __restrict__ w,
                      const float* __restrict__ bias, float* __restrict__ p) {
    __shared__ float wl[64 * 64];            // wl[ci*64+co]
    for (int k = threadIdx.x; k < 4096; k += 256) wl[k] = w[(k & 63) * 64 + (k >> 6)];
    __syncthreads();
    int b = blockIdx.x >> 7;
    int n0 = (blockIdx.x & 127) * 256 + threadIdx.x;
    float acc[64];
    #pragma unroll
    for (int co = 0; co < 64; ++co) acc[co] = 0.f;
    for (int ci = 0; ci < 64; ++ci) {
        float fv = f[((size_t)(b * 64 + ci)) * NPTS + n0];
        #pragma unroll
        for (int co = 0; co < 64; ++co) acc[co] += fv * wl[ci * 64 + co];
    }
    for (int co = 0; co < 64; ++co)
        p[((size_t)(b * 64 + co)) * NPTS + n0] = acc[co] + bias[co];
}

// stats for (B, C, N) layout: block per (b, c)
__global__ void k_stats_bcn(const float* __restrict__ x, float* __restrict__ stats) {
    int bc = blockIdx.x;                    // 512 blocks
    int c = bc & 63;
    const float* src = x + (size_t)bc * NPTS;
    float s = 0.f, s2 = 0.f;
    for (int i = threadIdx.x; i < NPTS; i += 256) { float v = src[i]; s += v; s2 += v * v; }
    __shared__ float red[512];
    red[threadIdx.x] = s; red[256 + threadIdx.x] = s2;
    __syncthreads();
    for (int w = 128; w > 0; w >>= 1) {
        if (threadIdx.x < w) {
            red[threadIdx.x] += red[threadIdx.x + w];
            red[256 + threadIdx.x] += red[256 + threadIdx.x + w];
        }
        __syncthreads();
    }
    if (threadIdx.x == 0) { atomicAdd(&stats[c], red[0]); atomicAdd(&stats[64 + c], red[256]); }
}

// fused BN(p)+leaky + trilinear devoxelize + add.
__global__ __launch_bounds__(256) void k_final(
    float* __restrict__ p, const float* __restrict__ stats,
    const float* __restrict__ g, const float* __restrict__ bb,
    const float* __restrict__ vgrid, const float* __restrict__ norm) {
    __shared__ float smp[64 * 65];
    int b = blockIdx.x >> 9;                 // 512 tiles per batch
    int n0 = (blockIdx.x & 511) * 64;
    int wid = threadIdx.x >> 6, lane = threadIdx.x & 63;
    const float* gb = vgrid + (((size_t)b) << 15) * CC;
    const float* nrm0 = norm + ((size_t)(b * 3)) * NPTS;

    #pragma unroll 2
    for (int i = 0; i < 16; ++i) {
        int pl = wid * 16 + i;
        int n = n0 + pl;
        float v0 = nrm0[n];
        float v1 = nrm0[NPTS + n];
        float v2 = nrm0[2 * NPTS + n];
        int lx = (int)floorf(v0), ly = (int)floorf(v1), lz = (int)floorf(v2);
        float fx = v0 - (float)lx, fy = v1 - (float)ly, fz = v2 - (float)lz;
        int hx = min(lx + 1, 31), hy = min(ly + 1, 31), hz = min(lz + 1, 31);
        float gx = 1.f - fx, gy = 1.f - fy, gz = 1.f - fz;

        int i000 = ((lx * 32 + ly) * 32 + lz) << 6;
        int i001 = ((lx * 32 + ly) * 32 + hz) << 6;
        int i010 = ((lx * 32 + hy) * 32 + lz) << 6;
        int i011 = ((lx * 32 + hy) * 32 + hz) << 6;
        int i100 = ((hx * 32 + ly) * 32 + lz) << 6;
        int i101 = ((hx * 32 + ly) * 32 + hz) << 6;
        int i110 = ((hx * 32 + hy) * 32 + lz) << 6;
        int i111 = ((hx * 32 + hy) * 32 + hz) << 6;

        float s = gb[i000 + lane] * (gx * gy * gz)
                + gb[i001 + lane] * (gx * gy * fz)
                + gb[i010 + lane] * (gx * fy * gz)
                + gb[i011 + lane] * (gx * fy * fz)
                + gb[i100 + lane] * (fx * gy * gz)
                + gb[i101 + lane] * (fx * gy * fz)
                + gb[i110 + lane] * (fx * fy * gz)
                + gb[i111 + lane] * (fx * fy * fz);
        smp[pl * 65 + lane] = s;
    }
    __syncthreads();

    #pragma unroll 4
    for (int i = 0; i < 16; ++i) {
        int co = i * 4 + wid;
        size_t pi = ((size_t)(b * 64 + co)) * NPTS + n0 + lane;
        float mu = stats[co] * (1.0f / MTOT);
        float var = stats[64 + co] * (1.0f / MTOT) - mu * mu;
        float pv = (p[pi] - mu) * rsqrtf(var + EPSV) * g[co] + bb[co];
        pv = pv > 0.f ? pv : 0.1f * pv;
        p[pi] = smp[lane * 65 + co] + pv;
    }
}

extern "C" void kernel_launch(void* const* d_in, const int* in_sizes, int n_in,
                              void* d_out, int out_size, void* d_ws, size_t ws_size,
                              hipStream_t stream) {
    const float* features = (const float*)d_in[0];
    const float* coords   = (const float*)d_in[1];
    const float* conv1_w  = (const float*)d_in[2];
    const float* conv1_b  = (const float*)d_in[3];
    const float* bn1_g    = (const float*)d_in[4];
    const float* bn1_b    = (const float*)d_in[5];
    const float* conv2_w  = (const float*)d_in[6];
    const float* conv2_b  = (const float*)d_in[7];
    const float* bn2_g    = (const float*)d_in[8];
    const float* bn2_b    = (const float*)d_in[9];
    const float* mlp_w    = (const float*)d_in[10];
    const float* mlp_b    = (const float*)d_in[11];
    const float* bnp_g    = (const float*)d_in[12];
    const float* bnp_b    = (const float*)d_in[13];

    float* ws    = (float*)d_ws;
    float* bufA  = ws + OFF_BUFA;
    float* bufB  = ws + OFF_BUFB;
    __hip_bfloat16* xb  = (__hip_bfloat16*)(ws + OFF_BUFB);
    __hip_bfloat16* wb1 = (__hip_bfloat16*)(ws + OFF_WB1);
    __hip_bfloat16* wb2 = (__hip_bfloat16*)(ws + OFF_WB2);
    float* zg    = ws + OFF_ZG;
    unsigned* base    = (unsigned*)(ws + OFF_BASE);
    unsigned* idxlist = (unsigned*)(ws + OFF_IDX);
    unsigned* aux     = (unsigned*)(ws + OFF_AUX);
    int* cellid       = (int*)(ws + OFF_CELL);
    unsigned* cnt     = (unsigned*)(ws + OFF_CNT);
    float* mean  = ws + OFF_MEAN;
    float* nrm   = ws + OFF_NORM;
    float* s1    = ws + OFF_S1;
    float* s2    = ws + OFF_S2;
    float* sp    = ws + OFF_SP;

    float* outF  = (float*)d_out;                       // fused region, also p scratch
    float* outV  = (float*)d_out + (size_t)16777216;    // v region, also conv1 raw-y scratch

    hipMemsetAsync(cnt, 0, 262144 * 4, stream);
    hipMemsetAsync(zg, 0, 256, stream);
    hipMemsetAsync(s1, 0, 384 * 4, stream);             // s1,s2,sp contiguous

    k_coord_mean<<<24, 256, 0, stream>>>(coords, mean);
    k_transposeF<<<4096, 256, 0, stream>>>(features, bufA);
    k_cellid<<<1024, 256, 0, stream>>>(coords, mean, nrm, cellid, cnt);
    k_scan1<<<256, 256, 0, stream>>>(cnt, base, aux);
    k_scan2<<<1, 256, 0, stream>>>(aux);
    k_scan3<<<1024, 256, 0, stream>>>(base, aux);
    k_scatter<<<1024, 256, 0, stream>>>(cellid, base, idxlist);
    k_gather<<<65536, 256, 0, stream>>>(bufA, idxlist, base, cnt, xb);

    k_wb<<<432, 256, 0, stream>>>(conv1_w, wb1);
    k_wb<<<432, 256, 0, stream>>>(conv2_w, wb2);

    // conv1: xb -> outV (raw y1, f32 NDHWC)
    k_conv_mfma<<<2048, 256, 0, stream>>>((const ushort*)xb, (const ushort*)wb1, conv1_b, outV);
    k_stats_ci<<<2048, 256, 0, stream>>>(outV, s1);
    k_bn_ci_bf16<<<65536, 256, 0, stream>>>(outV, s1, bn1_g, bn1_b, xb);   // x2 bf16 -> xb

    // conv2: xb -> bufA (raw y2)
    k_conv_mfma<<<2048, 256, 0, stream>>>((const ushort*)xb, (const ushort*)wb2, conv2_b, bufA);
    k_stats_ci<<<2048, 256, 0, stream>>>(bufA, s2);
    k_bn_ci_f32<<<65536, 256, 0, stream>>>(bufA, s2, bn2_g, bn2_b, bufB);  // v ndhwc f32 -> bufB

    // v -> d_out (NCDHW)
    k_transpose<<<4096, 256, 0, stream>>>(bufB, outV);

    // point branch: p -> outF
    k_mlp<<<1024, 256, 0, stream>>>(features, mlp_w, mlp_b, outF);
    k_stats_bcn<<<512, 256, 0, stream>>>(outF, sp);

    // fuse (in-place over p)
    k_final<<<4096, 256, 0, stream>>>(outF, sp, bnp_g, bnp_b, bufB, nrm);
}

// Round 7
// 712.397 us; speedup vs baseline: 43.6193x; 1.5109x over previous
//
#include <hip/hip_runtime.h>
#include <hip/hip_bf16.h>

#define BB 8
#define CC 64
#define NPTS 32768
#define RR 32
#define RV 32768            // 32^3
#define MTOT (BB*RV)        // 262144
#define EPSV 1e-4f

// ws float offsets
#define OFF_BUFA 0u               // 16777216 f32: featsT (B,N,C), later conv2 raw y2
#define OFF_BUFB 16777216u        // 16777216 f32: [0:8388608] = xb bf16 (x1)
#define OFF_WB1  25165824u        // 55296 float-slots = 110592 bf16
#define OFF_WB2  25221120u        // 55296
#define OFF_BASE 25276480u        // 262144 uint
#define OFF_IDX  25538624u        // 262144 uint
#define OFF_AUX  25800768u        // 256 uint
#define OFF_CELL 25801024u        // 262144 int
#define OFF_CNT  26063168u        // 262144 uint
#define OFF_MEAN 26325312u        // 24
#define OFF_PART1 26325504u       // 131072 (128 x 1024)
#define OFF_PART2 26456576u       // 131072
#define OFF_SCL1 26587648u        // 64
#define OFF_SFT1 26587712u        // 64
#define OFF_SCL2 26587776u        // 64
#define OFF_SFT2 26587840u        // 64
#define OFF_NORM 33554432u        // 786432 (survives to k_final)
#define OFF_SP   34341120u        // 128

typedef __attribute__((ext_vector_type(8))) __bf16 bf16x8;
typedef __attribute__((ext_vector_type(8))) unsigned short u16x8;
typedef __attribute__((ext_vector_type(4))) float f32x4;

__global__ void k_coord_mean(const float* __restrict__ coords, float* __restrict__ mean) {
    int ba = blockIdx.x;                 // b*3 + axis, 24 blocks
    const float* src = coords + (size_t)ba * NPTS;
    float s = 0.f;
    for (int i = threadIdx.x; i < NPTS; i += 256) s += src[i];
    __shared__ float red[256];
    red[threadIdx.x] = s; __syncthreads();
    for (int w = 128; w > 0; w >>= 1) {
        if (threadIdx.x < w) red[threadIdx.x] += red[threadIdx.x + w];
        __syncthreads();
    }
    if (threadIdx.x == 0) mean[ba] = red[0] * (1.0f / NPTS);
}

// feats (B,C,N) -> featsT (B,N,C) f32
__global__ void k_transposeF(const float* __restrict__ in, float* __restrict__ out) {
    __shared__ float t[64 * 65];
    int b = blockIdx.x >> 9;
    int n0 = (blockIdx.x & 511) * 64;
    #pragma unroll
    for (int k = 0; k < 16; ++k) {
        int idx = k * 256 + threadIdx.x;
        int c = idx >> 6, nl = idx & 63;
        t[c * 65 + nl] = in[((size_t)(b * 64 + c)) * NPTS + n0 + nl];
    }
    __syncthreads();
    #pragma unroll
    for (int k = 0; k < 16; ++k) {
        int idx = k * 256 + threadIdx.x;
        int nl = idx >> 6, c = idx & 63;
        out[((size_t)((b << 15) + n0 + nl)) * 64 + c] = t[c * 65 + nl];
    }
}

// per point: norm, cell id, count
__global__ void k_cellid(const float* __restrict__ coords, const float* __restrict__ mean,
                         float* __restrict__ norm, int* __restrict__ cellid,
                         unsigned* __restrict__ cnt) {
    int idx = blockIdx.x * 256 + threadIdx.x;      // b*NPTS + n
    int b = idx >> 15, n = idx & (NPTS - 1);
    int flat = 0;
    #pragma unroll
    for (int a = 0; a < 3; ++a) {
        float c = coords[((size_t)(b * 3 + a)) * NPTS + n];
        float nm = (c - mean[b * 3 + a] + 1.0f) * (0.5f * RR);
        nm = fminf(fmaxf(nm, 0.0f), (float)(RR - 1));
        norm[((size_t)(b * 3 + a)) * NPTS + n] = nm;
        flat = flat * RR + (int)rintf(nm);
    }
    int cell = b * RV + flat;
    cellid[idx] = cell;
    atomicAdd(&cnt[cell], 1u);
}

// block-local exclusive scan: 256 blocks x 1024 cells
__global__ void k_scan1(const unsigned* __restrict__ cnt, unsigned* __restrict__ base,
                        unsigned* __restrict__ aux) {
    int tid = threadIdx.x;
    int c0 = blockIdx.x * 1024 + tid * 4;
    unsigned v0 = cnt[c0], v1 = cnt[c0 + 1], v2 = cnt[c0 + 2], v3 = cnt[c0 + 3];
    unsigned tot = v0 + v1 + v2 + v3;
    __shared__ unsigned sc[256];
    sc[tid] = tot; __syncthreads();
    for (int off = 1; off < 256; off <<= 1) {
        unsigned t = (tid >= off) ? sc[tid - off] : 0u;
        __syncthreads();
        sc[tid] += t;
        __syncthreads();
    }
    unsigned excl = sc[tid] - tot;
    base[c0] = excl;
    base[c0 + 1] = excl + v0;
    base[c0 + 2] = excl + v0 + v1;
    base[c0 + 3] = excl + v0 + v1 + v2;
    if (tid == 255) aux[blockIdx.x] = sc[255];
}

__global__ void k_scan2(unsigned* __restrict__ aux) {
    int tid = threadIdx.x;
    unsigned own = aux[tid];
    __shared__ unsigned sc[256];
    sc[tid] = own; __syncthreads();
    for (int off = 1; off < 256; off <<= 1) {
        unsigned t = (tid >= off) ? sc[tid - off] : 0u;
        __syncthreads();
        sc[tid] += t;
        __syncthreads();
    }
    aux[tid] = sc[tid] - own;
}

__global__ void k_scan3(unsigned* __restrict__ base, const unsigned* __restrict__ aux) {
    int i = blockIdx.x * 256 + threadIdx.x;
    base[i] += aux[i >> 10];
}

// scatter point ids into per-cell segments (base becomes end-offset)
__global__ void k_scatter(const int* __restrict__ cellid, unsigned* __restrict__ base,
                          unsigned* __restrict__ idxlist) {
    int idx = blockIdx.x * 256 + threadIdx.x;
    int cell = cellid[idx];
    unsigned pos = atomicAdd(&base[cell], 1u);
    idxlist[pos] = (unsigned)idx;
}

// one wave per cell: average its points, write bf16 grid (B,vox,C)
__global__ __launch_bounds__(256) void k_gather(
    const float* __restrict__ featsT, const unsigned* __restrict__ idxlist,
    const unsigned* __restrict__ base, const unsigned* __restrict__ cnt,
    __hip_bfloat16* __restrict__ xb) {
    int cell = blockIdx.x * 4 + (threadIdx.x >> 6);
    int lane = threadIdx.x & 63;
    unsigned n = cnt[cell];
    unsigned start = base[cell] - n;
    float acc = 0.f;
    unsigned pid = (n > 0) ? idxlist[start] : 0u;
    for (unsigned i = 0; i < n;) {
        unsigned p = pid;
        ++i;
        if (i < n) pid = idxlist[start + i];
        acc += featsT[((size_t)p << 6) + lane];
    }
    float inv = (n > 0) ? (1.0f / (float)n) : 0.f;
    xb[((size_t)cell << 6) + lane] = __float2bfloat16(acc * inv);
}

// conv_w (co,ci,kd,kh,kw) -> wb[tap][co][ci] bf16
__global__ void k_wb(const float* __restrict__ w, __hip_bfloat16* __restrict__ wb) {
    int i = blockIdx.x * 256 + threadIdx.x;              // CC*CC*27
    if (i >= CC * CC * 27) return;
    int tap = i % 27, t = i / 27;
    int ci = t & 63, co = t >> 6;
    wb[((size_t)(tap * 64 + co)) * 64 + ci] = __float2bfloat16(w[i]);
}

// implicit-GEMM conv. block: 4x8x8 output tile (256 voxels) x 64 co, 4 waves;
// wave wid owns d-slice (64 voxels = 4 m-frags). halo 6x10x10 rows in LDS.
// MODE 0: src = bf16 NDHWC. MODE 1: src = f32 NDHWC, apply scl/sft + leaky, cvt bf16.
// epilogue: y = acc + bias; per-block per-channel sum/sumsq partials -> part[128][1024].
template<int MODE>
__global__ __launch_bounds__(256, 2) void k_conv_mfma(
    const void* __restrict__ src, const ushort* __restrict__ wb,
    const float* __restrict__ bias, const float* __restrict__ scl,
    const float* __restrict__ sft, float* __restrict__ y,
    float* __restrict__ part) {
    __shared__ __align__(16) char sh[600 * 128];         // 76800 B
    int tid = threadIdx.x;
    int twi = blockIdx.x & 3, thi = (blockIdx.x >> 2) & 3;
    int tdi = (blockIdx.x >> 4) & 7, b = blockIdx.x >> 7;
    int d0 = tdi * 4, h0 = thi * 8, w0 = twi * 8;

    float sc8[8], sf8[8];
    if (MODE == 1) {
        int off = tid & 7;
        #pragma unroll
        for (int j = 0; j < 8; ++j) { sc8[j] = scl[off * 8 + j]; sf8[j] = sft[off * 8 + j]; }
    }

    // stage halo: 600 rows x 8 chunks of 16B (bf16)
    for (int c = tid; c < 4800; c += 256) {
        int row = c >> 3, off = c & 7;
        int dz = row / 100, rem = row - dz * 100;
        int hz = rem / 10, wz = rem - hz * 10;
        int gd = d0 - 1 + dz, gh = h0 - 1 + hz, gw = w0 - 1 + wz;
        u16x8 v = {0, 0, 0, 0, 0, 0, 0, 0};
        if ((unsigned)gd < 32u && (unsigned)gh < 32u && (unsigned)gw < 32u) {
            size_t srco = (((size_t)((b << 15) | (gd << 10) | (gh << 5) | gw)) << 6) + off * 8;
            if (MODE == 0) {
                v = *reinterpret_cast<const u16x8*>((const ushort*)src + srco);
            } else {
                const float* yp = (const float*)src + srco;
                float4 f0 = *reinterpret_cast<const float4*>(yp);
                float4 f1 = *reinterpret_cast<const float4*>(yp + 4);
                float ff[8] = {f0.x, f0.y, f0.z, f0.w, f1.x, f1.y, f1.z, f1.w};
                #pragma unroll
                for (int j = 0; j < 8; ++j) {
                    float f = fmaf(ff[j], sc8[j], sf8[j]);
                    f = f > 0.f ? f : 0.1f * f;
                    __hip_bfloat16 hb = __float2bfloat16(f);
                    v[j] = *reinterpret_cast<unsigned short*>(&hb);
                }
            }
        }
        int la = ((row << 7) + (off << 4)) ^ ((row & 7) << 4);
        *reinterpret_cast<u16x8*>(sh + la) = v;
    }
    __syncthreads();

    int lane = tid & 63, wid = tid >> 6;
    int nl = lane & 15, kg = lane >> 4;
    int rbase = wid * 100 + (nl >> 3) * 10 + (nl & 7);
    const ushort* wbase = wb + nl * 64 + kg * 8;

    f32x4 acc[4][4];
    #pragma unroll
    for (int mi = 0; mi < 4; ++mi)
        #pragma unroll
        for (int cb = 0; cb < 4; ++cb) acc[mi][cb] = (f32x4){0.f, 0.f, 0.f, 0.f};

    #pragma unroll 1
    for (int kd = 0; kd < 3; ++kd) {
        #pragma unroll
        for (int kh = 0; kh < 3; ++kh) {
            #pragma unroll
            for (int kw = 0; kw < 3; ++kw) {
                int rr = rbase + kd * 100 + kh * 10 + kw;
                bf16x8 a[4][2];
                #pragma unroll
                for (int mi = 0; mi < 4; ++mi) {
                    int r = rr + mi * 20;
                    int ba = ((r << 7) + (kg << 4)) ^ ((r & 7) << 4);
                    a[mi][0] = *reinterpret_cast<const bf16x8*>(sh + ba);
                    a[mi][1] = *reinterpret_cast<const bf16x8*>(sh + (ba ^ 64));
                }
                int tap = (kd * 3 + kh) * 3 + kw;
                const ushort* wt = wbase + tap * 4096;
                bf16x8 bf[4][2];
                #pragma unroll
                for (int cb = 0; cb < 4; ++cb) {
                    bf[cb][0] = *reinterpret_cast<const bf16x8*>(wt + cb * 1024);
                    bf[cb][1] = *reinterpret_cast<const bf16x8*>(wt + cb * 1024 + 32);
                }
                #pragma unroll
                for (int ks = 0; ks < 2; ++ks)
                    #pragma unroll
                    for (int mi = 0; mi < 4; ++mi)
                        #pragma unroll
                        for (int cb = 0; cb < 4; ++cb)
                            acc[mi][cb] = __builtin_amdgcn_mfma_f32_16x16x32_bf16(
                                a[mi][ks], bf[cb][ks], acc[mi][cb], 0, 0, 0);
            }
        }
    }

    int d = d0 + wid;
    float bs[4];
    #pragma unroll
    for (int cb = 0; cb < 4; ++cb) bs[cb] = bias[cb * 16 + nl];
    float ss[4] = {0.f, 0.f, 0.f, 0.f}, qq[4] = {0.f, 0.f, 0.f, 0.f};
    #pragma unroll
    for (int mi = 0; mi < 4; ++mi) {
        int h = h0 + mi * 2 + (kg >> 1);
        int w = w0 + (kg & 1) * 4;
        size_t vox = (size_t)((b << 15) | (d << 10) | (h << 5) | w);
        #pragma unroll
        for (int cb = 0; cb < 4; ++cb) {
            int co = cb * 16 + nl;
            #pragma unroll
            for (int r = 0; r < 4; ++r) {
                float yv = acc[mi][cb][r] + bs[cb];
                y[((vox + r) << 6) + co] = yv;
                ss[cb] += yv; qq[cb] += yv * yv;
            }
        }
    }
    #pragma unroll
    for (int cb = 0; cb < 4; ++cb) {
        ss[cb] += __shfl_xor(ss[cb], 16); ss[cb] += __shfl_xor(ss[cb], 32);
        qq[cb] += __shfl_xor(qq[cb], 16); qq[cb] += __shfl_xor(qq[cb], 32);
    }
    __syncthreads();
    float* sf = (float*)sh;
    if (lane < 16) {
        #pragma unroll
        for (int cb = 0; cb < 4; ++cb) {
            sf[wid * 128 + cb * 16 + nl] = ss[cb];
            sf[wid * 128 + 64 + cb * 16 + nl] = qq[cb];
        }
    }
    __syncthreads();
    if (tid < 128) {
        float t = sf[tid] + sf[128 + tid] + sf[256 + tid] + sf[384 + tid];
        part[tid * 1024 + blockIdx.x] = t;
    }
}

// reduce partials -> BN affine (scl, sft). 64 blocks, block = one channel.
__global__ void k_redbn(const float* __restrict__ part, const float* __restrict__ g,
                        const float* __restrict__ bb, float* __restrict__ scl,
                        float* __restrict__ sft) {
    int c = blockIdx.x;
    float s = 0.f, q = 0.f;
    for (int i = threadIdx.x; i < 1024; i += 256) {
        s += part[c * 1024 + i];
        q += part[(64 + c) * 1024 + i];
    }
    __shared__ float rs[256], rq[256];
    rs[threadIdx.x] = s; rq[threadIdx.x] = q; __syncthreads();
    for (int w = 128; w > 0; w >>= 1) {
        if (threadIdx.x < w) { rs[threadIdx.x] += rs[threadIdx.x + w]; rq[threadIdx.x] += rq[threadIdx.x + w]; }
        __syncthreads();
    }
    if (threadIdx.x == 0) {
        float mu = rs[0] * (1.0f / MTOT);
        float var = rq[0] * (1.0f / MTOT) - mu * mu;
        float sc = g[c] * rsqrtf(var + EPSV);
        scl[c] = sc; sft[c] = bb[c] - mu * sc;
    }
}

// y2 NDHWC -> v NCDHW with BN2 affine + leaky fused
__global__ void k_transpose(const float* __restrict__ in, const float* __restrict__ scl,
                            const float* __restrict__ sft, float* __restrict__ out) {
    __shared__ float t[64 * 65];
    size_t base = (size_t)blockIdx.x * 4096;
    int gv0 = blockIdx.x * 64;
    int b = gv0 >> 15;
    int vox0 = gv0 & 32767;
    int chl = threadIdx.x & 63;
    float sc = scl[chl], sf = sft[chl];
    #pragma unroll
    for (int k = 0; k < 16; ++k) {
        int idx = k * 256 + threadIdx.x;
        float v = fmaf(in[base + idx], sc, sf);
        t[(idx >> 6) * 65 + (idx & 63)] = v > 0.f ? v : 0.1f * v;
    }
    __syncthreads();
    #pragma unroll
    for (int k = 0; k < 16; ++k) {
        int idx = k * 256 + threadIdx.x;
        int ch = idx >> 6, voxl = idx & 63;
        out[((size_t)(b * 64 + ch)) * RV + vox0 + voxl] = t[voxl * 65 + ch];
    }
}

__global__ void k_mlp(const float* __restrict__ f, const float* __restrict__ w,
                      const float* __restrict__ bias, float* __restrict__ p) {
    __shared__ float wl[64 * 64];            // wl[ci*64+co]
    for (int k = threadIdx.x; k < 4096; k += 256) wl[k] = w[(k & 63) * 64 + (k >> 6)];
    __syncthreads();
    int b = blockIdx.x >> 7;
    int n0 = (blockIdx.x & 127) * 256 + threadIdx.x;
    float acc[64];
    #pragma unroll
    for (int co = 0; co < 64; ++co) acc[co] = 0.f;
    for (int ci = 0; ci < 64; ++ci) {
        float fv = f[((size_t)(b * 64 + ci)) * NPTS + n0];
        #pragma unroll
        for (int co = 0; co < 64; ++co) acc[co] += fv * wl[ci * 64 + co];
    }
    for (int co = 0; co < 64; ++co)
        p[((size_t)(b * 64 + co)) * NPTS + n0] = acc[co] + bias[co];
}

// stats for (B, C, N) layout: block per (b, c)
__global__ void k_stats_bcn(const float* __restrict__ x, float* __restrict__ stats) {
    int bc = blockIdx.x;                    // 512 blocks
    int c = bc & 63;
    const float* src = x + (size_t)bc * NPTS;
    float s = 0.f, s2 = 0.f;
    for (int i = threadIdx.x; i < NPTS; i += 256) { float v = src[i]; s += v; s2 += v * v; }
    __shared__ float red[512];
    red[threadIdx.x] = s; red[256 + threadIdx.x] = s2;
    __syncthreads();
    for (int w = 128; w > 0; w >>= 1) {
        if (threadIdx.x < w) {
            red[threadIdx.x] += red[threadIdx.x + w];
            red[256 + threadIdx.x] += red[256 + threadIdx.x + w];
        }
        __syncthreads();
    }
    if (threadIdx.x == 0) { atomicAdd(&stats[c], red[0]); atomicAdd(&stats[64 + c], red[256]); }
}

// fused BN(p)+leaky + trilinear devoxelize (raw y2 + BN2 affine + leaky) + add.
__global__ __launch_bounds__(256) void k_final(
    float* __restrict__ p, const float* __restrict__ stats,
    const float* __restrict__ g, const float* __restrict__ bb,
    const float* __restrict__ vraw, const float* __restrict__ norm,
    const float* __restrict__ scl, const float* __restrict__ sft) {
    __shared__ float smp[64 * 65];
    int b = blockIdx.x >> 9;                 // 512 tiles per batch
    int n0 = (blockIdx.x & 511) * 64;
    int wid = threadIdx.x >> 6, lane = threadIdx.x & 63;
    const float* gb = vraw + (((size_t)b) << 15) * CC;
    const float* nrm0 = norm + ((size_t)(b * 3)) * NPTS;
    float sc = scl[lane], sf = sft[lane];

    #pragma unroll 2
    for (int i = 0; i < 16; ++i) {
        int pl = wid * 16 + i;
        int n = n0 + pl;
        float v0 = nrm0[n];
        float v1 = nrm0[NPTS + n];
        float v2 = nrm0[2 * NPTS + n];
        int lx = (int)floorf(v0), ly = (int)floorf(v1), lz = (int)floorf(v2);
        float fx = v0 - (float)lx, fy = v1 - (float)ly, fz = v2 - (float)lz;
        int hx = min(lx + 1, 31), hy = min(ly + 1, 31), hz = min(lz + 1, 31);
        float gx = 1.f - fx, gy = 1.f - fy, gz = 1.f - fz;

        int i000 = ((lx * 32 + ly) * 32 + lz) << 6;
        int i001 = ((lx * 32 + ly) * 32 + hz) << 6;
        int i010 = ((lx * 32 + hy) * 32 + lz) << 6;
        int i011 = ((lx * 32 + hy) * 32 + hz) << 6;
        int i100 = ((hx * 32 + ly) * 32 + lz) << 6;
        int i101 = ((hx * 32 + ly) * 32 + hz) << 6;
        int i110 = ((hx * 32 + hy) * 32 + lz) << 6;
        int i111 = ((hx * 32 + hy) * 32 + hz) << 6;

        float w000 = gx * gy * gz, w001 = gx * gy * fz;
        float w010 = gx * fy * gz, w011 = gx * fy * fz;
        float w100 = fx * gy * gz, w101 = fx * gy * fz;
        float w110 = fx * fy * gz, w111 = fx * fy * fz;

        float r0 = fmaf(gb[i000 + lane], sc, sf); r0 = r0 > 0.f ? r0 : 0.1f * r0;
        float r1 = fmaf(gb[i001 + lane], sc, sf); r1 = r1 > 0.f ? r1 : 0.1f * r1;
        float r2 = fmaf(gb[i010 + lane], sc, sf); r2 = r2 > 0.f ? r2 : 0.1f * r2;
        float r3 = fmaf(gb[i011 + lane], sc, sf); r3 = r3 > 0.f ? r3 : 0.1f * r3;
        float r4 = fmaf(gb[i100 + lane], sc, sf); r4 = r4 > 0.f ? r4 : 0.1f * r4;
        float r5 = fmaf(gb[i101 + lane], sc, sf); r5 = r5 > 0.f ? r5 : 0.1f * r5;
        float r6 = fmaf(gb[i110 + lane], sc, sf); r6 = r6 > 0.f ? r6 : 0.1f * r6;
        float r7 = fmaf(gb[i111 + lane], sc, sf); r7 = r7 > 0.f ? r7 : 0.1f * r7;

        float s = r0 * w000 + r1 * w001 + r2 * w010 + r3 * w011
                + r4 * w100 + r5 * w101 + r6 * w110 + r7 * w111;
        smp[pl * 65 + lane] = s;
    }
    __syncthreads();

    #pragma unroll 4
    for (int i = 0; i < 16; ++i) {
        int co = i * 4 + wid;
        size_t pi = ((size_t)(b * 64 + co)) * NPTS + n0 + lane;
        float mu = stats[co] * (1.0f / MTOT);
        float var = stats[64 + co] * (1.0f / MTOT) - mu * mu;
        float pv = (p[pi] - mu) * rsqrtf(var + EPSV) * g[co] + bb[co];
        pv = pv > 0.f ? pv : 0.1f * pv;
        p[pi] = smp[lane * 65 + co] + pv;
    }
}

extern "C" void kernel_launch(void* const* d_in, const int* in_sizes, int n_in,
                              void* d_out, int out_size, void* d_ws, size_t ws_size,
                              hipStream_t stream) {
    const float* features = (const float*)d_in[0];
    const float* coords   = (const float*)d_in[1];
    const float* conv1_w  = (const float*)d_in[2];
    const float* conv1_b  = (const float*)d_in[3];
    const float* bn1_g    = (const float*)d_in[4];
    const float* bn1_b    = (const float*)d_in[5];
    const float* conv2_w  = (const float*)d_in[6];
    const float* conv2_b  = (const float*)d_in[7];
    const float* bn2_g    = (const float*)d_in[8];
    const float* bn2_b    = (const float*)d_in[9];
    const float* mlp_w    = (const float*)d_in[10];
    const float* mlp_b    = (const float*)d_in[11];
    const float* bnp_g    = (const float*)d_in[12];
    const float* bnp_b    = (const float*)d_in[13];

    float* ws    = (float*)d_ws;
    float* bufA  = ws + OFF_BUFA;
    __hip_bfloat16* xb  = (__hip_bfloat16*)(ws + OFF_BUFB);
    __hip_bfloat16* wb1 = (__hip_bfloat16*)(ws + OFF_WB1);
    __hip_bfloat16* wb2 = (__hip_bfloat16*)(ws + OFF_WB2);
    unsigned* base    = (unsigned*)(ws + OFF_BASE);
    unsigned* idxlist = (unsigned*)(ws + OFF_IDX);
    unsigned* aux     = (unsigned*)(ws + OFF_AUX);
    int* cellid       = (int*)(ws + OFF_CELL);
    unsigned* cnt     = (unsigned*)(ws + OFF_CNT);
    float* mean  = ws + OFF_MEAN;
    float* part1 = ws + OFF_PART1;
    float* part2 = ws + OFF_PART2;
    float* scl1  = ws + OFF_SCL1;
    float* sft1  = ws + OFF_SFT1;
    float* scl2  = ws + OFF_SCL2;
    float* sft2  = ws + OFF_SFT2;
    float* nrm   = ws + OFF_NORM;
    float* sp    = ws + OFF_SP;

    float* outF  = (float*)d_out;                       // fused region, also p scratch
    float* outV  = (float*)d_out + (size_t)16777216;    // v region, also raw y1 scratch

    hipMemsetAsync(cnt, 0, 262144 * 4, stream);
    hipMemsetAsync(sp, 0, 128 * 4, stream);

    k_coord_mean<<<24, 256, 0, stream>>>(coords, mean);
    k_transposeF<<<4096, 256, 0, stream>>>(features, bufA);
    k_cellid<<<1024, 256, 0, stream>>>(coords, mean, nrm, cellid, cnt);
    k_scan1<<<256, 256, 0, stream>>>(cnt, base, aux);
    k_scan2<<<1, 256, 0, stream>>>(aux);
    k_scan3<<<1024, 256, 0, stream>>>(base, aux);
    k_scatter<<<1024, 256, 0, stream>>>(cellid, base, idxlist);
    k_gather<<<65536, 256, 0, stream>>>(bufA, idxlist, base, cnt, xb);

    k_wb<<<432, 256, 0, stream>>>(conv1_w, wb1);
    k_wb<<<432, 256, 0, stream>>>(conv2_w, wb2);

    // conv1: xb (bf16) -> outV (raw y1 f32 NDHWC) + moment partials
    k_conv_mfma<0><<<1024, 256, 0, stream>>>((const void*)xb, (const ushort*)wb1, conv1_b,
                                             nullptr, nullptr, outV, part1);
    k_redbn<<<64, 256, 0, stream>>>(part1, bn1_g, bn1_b, scl1, sft1);

    // conv2: stages raw y1 + BN1 affine + leaky -> bf16 in-register; out raw y2 -> bufA
    k_conv_mfma<1><<<1024, 256, 0, stream>>>((const void*)outV, (const ushort*)wb2, conv2_b,
                                             scl1, sft1, bufA, part2);
    k_redbn<<<64, 256, 0, stream>>>(part2, bn2_g, bn2_b, scl2, sft2);

    // v = leaky(bn2(y2)) -> d_out NCDHW (overwrites y1 region)
    k_transpose<<<4096, 256, 0, stream>>>(bufA, scl2, sft2, outV);

    // point branch: p -> outF
    k_mlp<<<1024, 256, 0, stream>>>(features, mlp_w, mlp_b, outF);
    k_stats_bcn<<<512, 256, 0, stream>>>(outF, sp);

    // fuse (in-place over p), trilinear from raw y2 + fused BN2
    k_final<<<4096, 256, 0, stream>>>(outF, sp, bnp_g, bnp_b, bufA, nrm, scl2, sft2);
}